// Round 1
// baseline (3440.626 us; speedup 1.0000x reference)
//
#include <hip/hip_runtime.h>

#define N_NODES 100000
#define N_EDGES 1200000
#define D 64
#define NUM_LAYERS 3

// ---------------- degree / norm precompute ----------------

__global__ void deg_kernel(const int* __restrict__ src, float* __restrict__ deg, int E) {
    int i = blockIdx.x * blockDim.x + threadIdx.x;
    int stride = gridDim.x * blockDim.x;
    for (; i < E; i += stride) {
        unsigned s = (unsigned)src[i];
        if (s < N_NODES) atomicAdd(&deg[s], 1.0f);
    }
}

__global__ void dinv_kernel(float* __restrict__ deg, int n) {
    int i = blockIdx.x * blockDim.x + threadIdx.x;
    if (i < n) {
        float d = deg[i];
        deg[i] = (d > 0.0f) ? rsqrtf(fmaxf(d, 1.0f)) : 0.0f;
    }
}

__global__ void norm_kernel(const int* __restrict__ src, const int* __restrict__ dst,
                            const float* __restrict__ dinv, float* __restrict__ norm, int E) {
    int i = blockIdx.x * blockDim.x + threadIdx.x;
    int stride = gridDim.x * blockDim.x;
    for (; i < E; i += stride) {
        unsigned s = (unsigned)src[i];
        unsigned t = (unsigned)dst[i];
        float v = 0.0f;
        if (s < N_NODES && t < N_NODES) v = -dinv[s] * dinv[t];
        norm[i] = v;
    }
}

// ---------------- propagate: out[dst] += norm * h[src] ----------------
// one wave (64 lanes) per edge; lane = feature index

__global__ __launch_bounds__(256) void scatter_kernel(
        const int* __restrict__ src, const int* __restrict__ dst,
        const float* __restrict__ norm, const float* __restrict__ h,
        float* __restrict__ out, int E) {
    int lane = threadIdx.x & 63;
    int wid = threadIdx.x >> 6;
    int wpb = blockDim.x >> 6;
    int e = blockIdx.x * wpb + wid;
    int stride = gridDim.x * wpb;
    for (; e < E; e += stride) {
        unsigned s = (unsigned)src[e];
        unsigned t = (unsigned)dst[e];
        if (s >= N_NODES || t >= N_NODES) continue;
        float nv = norm[e];
        float v = nv * h[(size_t)s * D + lane];
        atomicAdd(&out[(size_t)t * D + lane], v);
    }
}

// ---------------- fused per-layer epilogue ----------------
// out[n,:] = relu( Tx0@W0 + Tx1@W1 + (2*Tx2 - Tx0)@W2 + b (+ skip*Tx0) )
// one wave per node, lane = output feature j; weights staged in LDS.

__global__ __launch_bounds__(256) void cheb_out_kernel(
        const float* __restrict__ inp, const float* __restrict__ t1,
        const float* __restrict__ t2, const float* __restrict__ W,
        const float* __restrict__ bias, float* __restrict__ out,
        int n, int addSkip) {
    __shared__ float sW0[D * D];
    __shared__ float sW1[D * D];
    __shared__ float sW2[D * D];
    for (int i = threadIdx.x; i < D * D; i += blockDim.x) {
        sW0[i] = W[i];
        sW1[i] = W[D * D + i];
        sW2[i] = W[2 * D * D + i];
    }
    __syncthreads();

    int lane = threadIdx.x & 63;
    int wid = threadIdx.x >> 6;
    int wpb = blockDim.x >> 6;
    float bj = bias[lane];

    for (int node = blockIdx.x * wpb + wid; node < n; node += gridDim.x * wpb) {
        size_t base = (size_t)node * D;
        float a0 = inp[base + lane];
        float a1 = t1[base + lane];
        float x2 = 2.0f * t2[base + lane] - a0;
        float acc = 0.0f;
#pragma unroll
        for (int k = 0; k < D; ++k) {
            float v0 = __shfl(a0, k);
            float v1 = __shfl(a1, k);
            float v2 = __shfl(x2, k);
            acc = fmaf(v0, sW0[k * D + lane], acc);
            acc = fmaf(v1, sW1[k * D + lane], acc);
            acc = fmaf(v2, sW2[k * D + lane], acc);
        }
        float o = acc + bj + (addSkip ? a0 : 0.0f);
        out[base + lane] = fmaxf(o, 0.0f);
    }
}

extern "C" void kernel_launch(void* const* d_in, const int* in_sizes, int n_in,
                              void* d_out, int out_size, void* d_ws, size_t ws_size,
                              hipStream_t stream) {
    const float* x = (const float*)d_in[0];
    const int* ei = (const int*)d_in[1];
    const float* W = (const float*)d_in[2];   // [3,3,64,64]
    const float* b = (const float*)d_in[3];   // [3,64]
    float* out = (float*)d_out;

    const int* src = ei;             // edge_index[0]
    const int* dst = ei + N_EDGES;   // edge_index[1]

    float* dinv = (float*)d_ws;                       // N
    float* norm = dinv + N_NODES;                     // E
    float* h    = norm + N_EDGES;                     // N*D
    float* t1   = h + (size_t)N_NODES * D;            // N*D
    float* t2   = t1 + (size_t)N_NODES * D;           // N*D

    // degree -> deg_inv_sqrt -> per-edge norm
    hipMemsetAsync(dinv, 0, N_NODES * sizeof(float), stream);
    deg_kernel<<<2048, 256, 0, stream>>>(src, dinv, N_EDGES);
    dinv_kernel<<<(N_NODES + 255) / 256, 256, 0, stream>>>(dinv, N_NODES);
    norm_kernel<<<2048, 256, 0, stream>>>(src, dst, dinv, norm, N_EDGES);

    const float* inp = x;
    for (int l = 0; l < NUM_LAYERS; ++l) {
        hipMemsetAsync(t1, 0, (size_t)N_NODES * D * sizeof(float), stream);
        scatter_kernel<<<2048, 256, 0, stream>>>(src, dst, norm, inp, t1, N_EDGES);
        hipMemsetAsync(t2, 0, (size_t)N_NODES * D * sizeof(float), stream);
        scatter_kernel<<<2048, 256, 0, stream>>>(src, dst, norm, t1, t2, N_EDGES);

        float* o = (l == NUM_LAYERS - 1) ? out : h;
        cheb_out_kernel<<<1024, 256, 0, stream>>>(
            inp, t1, t2, W + (size_t)l * 3 * D * D, b + (size_t)l * D, o,
            N_NODES, l > 0 ? 1 : 0);
        inp = h;
    }
}

// Round 2
// 1842.049 us; speedup vs baseline: 1.8678x; 1.8678x over previous
//
#include <hip/hip_runtime.h>

#define N_NODES 100000
#define N_EDGES 1200000
#define D 64
#define NUM_LAYERS 3

// ---------------- degree / norm precompute ----------------

__global__ void deg_kernel(const int* __restrict__ src, float* __restrict__ deg, int E) {
    int i = blockIdx.x * blockDim.x + threadIdx.x;
    int stride = gridDim.x * blockDim.x;
    for (; i < E; i += stride) {
        unsigned s = (unsigned)src[i];
        if (s < N_NODES) atomicAdd(&deg[s], 1.0f);
    }
}

__global__ void dinv_kernel(float* __restrict__ deg, int n) {
    int i = blockIdx.x * blockDim.x + threadIdx.x;
    if (i < n) {
        float d = deg[i];
        deg[i] = (d > 0.0f) ? rsqrtf(fmaxf(d, 1.0f)) : 0.0f;
    }
}

__global__ void norm_kernel(const int* __restrict__ src, const int* __restrict__ dst,
                            const float* __restrict__ dinv, float* __restrict__ norm, int E) {
    int i = blockIdx.x * blockDim.x + threadIdx.x;
    int stride = gridDim.x * blockDim.x;
    for (; i < E; i += stride) {
        unsigned s = (unsigned)src[i];
        unsigned t = (unsigned)dst[i];
        float v = 0.0f;
        if (s < N_NODES && t < N_NODES) v = -dinv[s] * dinv[t];
        norm[i] = v;
    }
}

// ---------------- propagate: out[dst] += norm * h[src] ----------------
// one wave (64 lanes) per edge; lane = feature index

__global__ __launch_bounds__(256) void scatter_kernel(
        const int* __restrict__ src, const int* __restrict__ dst,
        const float* __restrict__ norm, const float* __restrict__ h,
        float* __restrict__ out, int E) {
    int lane = threadIdx.x & 63;
    int wid = threadIdx.x >> 6;
    int wpb = blockDim.x >> 6;
    int e = blockIdx.x * wpb + wid;
    int stride = gridDim.x * wpb;
    for (; e < E; e += stride) {
        unsigned s = (unsigned)src[e];
        unsigned t = (unsigned)dst[e];
        if (s >= N_NODES || t >= N_NODES) continue;
        float nv = norm[e];
        float v = nv * h[(size_t)s * D + lane];
        atomicAdd(&out[(size_t)t * D + lane], v);
    }
}

// ---------------- fused per-layer epilogue ----------------
// out[n,:] = relu( [Tx0 | Tx1 | 2*Tx2-Tx0] @ Wcat + b (+ skip) )
// Wcat = layer weights [3,64,64] viewed as [192,64] (row = (k,in)).
// Block = 256 threads = 4 waves. Tile = 64 nodes staged in LDS (stride 193).
// lane = node within tile; wave = 16-output-feature group; acc[16] in VGPRs.
// Weight rows are wave-uniform -> scalar loads (s_load_dwordx16).

#define XSTRIDE 193

__global__ __launch_bounds__(256) void cheb_out_kernel(
        const float* __restrict__ inp, const float* __restrict__ t1,
        const float* __restrict__ t2, const float* __restrict__ W,
        const float* __restrict__ bias, float* __restrict__ out,
        int n, int addSkip) {
    __shared__ float sX[64 * XSTRIDE];
    const int t = threadIdx.x;
    const int lane = t & 63;
    const int jbase = __builtin_amdgcn_readfirstlane(((t >> 6) & 3) * 16);

    for (int tile = blockIdx.x; tile * 64 < n; tile += gridDim.x) {
        const int base = tile * 64;
        const int nNodes = min(64, n - base);

        __syncthreads();
        // stage 64 nodes x 192 cols: [inp | t1 | 2*t2 - inp]
#pragma unroll
        for (int a = 0; a < 4; ++a) {
            int idx = a * 256 + t;        // 0..1023
            int node = idx >> 4;          // 0..63
            int c = (idx & 15) * 4;       // 0..60
            if (node < nNodes) {
                size_t g = (size_t)(base + node) * D + c;
                float4 i4 = *(const float4*)&inp[g];
                float4 a4 = *(const float4*)&t1[g];
                float4 b4 = *(const float4*)&t2[g];
                float* p = &sX[node * XSTRIDE + c];
                p[0] = i4.x; p[1] = i4.y; p[2] = i4.z; p[3] = i4.w;
                p[64] = a4.x; p[65] = a4.y; p[66] = a4.z; p[67] = a4.w;
                p[128] = fmaf(2.0f, b4.x, -i4.x);
                p[129] = fmaf(2.0f, b4.y, -i4.y);
                p[130] = fmaf(2.0f, b4.z, -i4.z);
                p[131] = fmaf(2.0f, b4.w, -i4.w);
            }
        }
        __syncthreads();

        float acc[16];
#pragma unroll
        for (int j = 0; j < 16; ++j) acc[j] = 0.0f;

        const float* __restrict__ xrow = &sX[lane * XSTRIDE];
#pragma unroll 4
        for (int r = 0; r < 3 * D; ++r) {
            float xv = xrow[r];
            const float* wr = W + (r << 6) + jbase;   // wave-uniform -> s_load
#pragma unroll
            for (int j = 0; j < 16; ++j) acc[j] = fmaf(xv, wr[j], acc[j]);
        }

        if (lane < nNodes) {
            size_t ob = (size_t)(base + lane) * D + jbase;
#pragma unroll
            for (int j = 0; j < 16; ++j) {
                float o = acc[j] + bias[jbase + j];
                if (addSkip) o += xrow[jbase + j];   // skip = inp row (h_prev)
                out[ob + j] = fmaxf(o, 0.0f);
            }
        }
    }
}

extern "C" void kernel_launch(void* const* d_in, const int* in_sizes, int n_in,
                              void* d_out, int out_size, void* d_ws, size_t ws_size,
                              hipStream_t stream) {
    const float* x = (const float*)d_in[0];
    const int* ei = (const int*)d_in[1];
    const float* W = (const float*)d_in[2];   // [3,3,64,64]
    const float* b = (const float*)d_in[3];   // [3,64]
    float* out = (float*)d_out;

    const int* src = ei;             // edge_index[0]
    const int* dst = ei + N_EDGES;   // edge_index[1]

    float* dinv = (float*)d_ws;                       // N
    float* norm = dinv + N_NODES;                     // E
    float* h    = norm + N_EDGES;                     // N*D
    float* t1   = h + (size_t)N_NODES * D;            // N*D
    float* t2   = t1 + (size_t)N_NODES * D;           // N*D

    // degree -> deg_inv_sqrt -> per-edge norm
    hipMemsetAsync(dinv, 0, N_NODES * sizeof(float), stream);
    deg_kernel<<<2048, 256, 0, stream>>>(src, dinv, N_EDGES);
    dinv_kernel<<<(N_NODES + 255) / 256, 256, 0, stream>>>(dinv, N_NODES);
    norm_kernel<<<2048, 256, 0, stream>>>(src, dst, dinv, norm, N_EDGES);

    const int nTiles = (N_NODES + 63) / 64;   // 1563

    const float* inp = x;
    for (int l = 0; l < NUM_LAYERS; ++l) {
        hipMemsetAsync(t1, 0, (size_t)N_NODES * D * sizeof(float), stream);
        scatter_kernel<<<2048, 256, 0, stream>>>(src, dst, norm, inp, t1, N_EDGES);
        hipMemsetAsync(t2, 0, (size_t)N_NODES * D * sizeof(float), stream);
        scatter_kernel<<<2048, 256, 0, stream>>>(src, dst, norm, t1, t2, N_EDGES);

        float* o = (l == NUM_LAYERS - 1) ? out : h;
        cheb_out_kernel<<<nTiles, 256, 0, stream>>>(
            inp, t1, t2, W + (size_t)l * 3 * D * D, b + (size_t)l * D, o,
            N_NODES, l > 0 ? 1 : 0);
        inp = h;
    }
}

// Round 3
// 825.698 us; speedup vs baseline: 4.1669x; 2.2309x over previous
//
#include <hip/hip_runtime.h>

#define N_NODES 100000
#define N_EDGES 1200000
#define D 64
#define NUM_LAYERS 3
#define SCAN_TILE 1024

// ---------------- degree count (both directions) ----------------

__global__ void deg2_kernel(const int* __restrict__ src, const int* __restrict__ dst,
                            int* __restrict__ degs, int* __restrict__ degd, int E) {
    int i = blockIdx.x * blockDim.x + threadIdx.x;
    int stride = gridDim.x * blockDim.x;
    for (; i < E; i += stride) {
        unsigned s = (unsigned)src[i];
        unsigned t = (unsigned)dst[i];
        if (s < N_NODES) atomicAdd(&degs[s], 1);
        if (t < N_NODES) atomicAdd(&degd[t], 1);
    }
}

__global__ void dinv_kernel(const int* __restrict__ degs, float* __restrict__ dinv, int n) {
    int i = blockIdx.x * blockDim.x + threadIdx.x;
    if (i < n) {
        int d = degs[i];
        dinv[i] = (d > 0) ? rsqrtf((float)d) : 0.0f;
    }
}

// ---------------- exclusive scan of degd -> rowptr (3 kernels) ----------------

__global__ __launch_bounds__(256) void tile_sum_kernel(const int* __restrict__ degd,
                                                       int* __restrict__ tsum, int n) {
    __shared__ int wsum[4];
    int b = blockIdx.x, t = threadIdx.x;
    int i0 = b * SCAN_TILE + t * 4;
    int s = 0;
#pragma unroll
    for (int k = 0; k < 4; ++k)
        if (i0 + k < n) s += degd[i0 + k];
#pragma unroll
    for (int off = 32; off > 0; off >>= 1) s += __shfl_down(s, off);
    int lane = t & 63, wid = t >> 6;
    if (lane == 0) wsum[wid] = s;
    __syncthreads();
    if (t == 0) tsum[b] = wsum[0] + wsum[1] + wsum[2] + wsum[3];
}

__global__ void tscan_kernel(int* __restrict__ tsum, int ntiles, int* __restrict__ rowptr_last) {
    if (blockIdx.x == 0 && threadIdx.x == 0) {
        int run = 0;
        for (int i = 0; i < ntiles; ++i) { int v = tsum[i]; tsum[i] = run; run += v; }
        rowptr_last[0] = run;
    }
}

__global__ __launch_bounds__(256) void scan_kernel(const int* __restrict__ degd,
        const int* __restrict__ tbase, int* __restrict__ rowptr,
        int* __restrict__ cursor, int n) {
    __shared__ int wsum[4];
    int b = blockIdx.x, t = threadIdx.x;
    int i0 = b * SCAN_TILE + t * 4;
    int v0 = (i0 + 0 < n) ? degd[i0 + 0] : 0;
    int v1 = (i0 + 1 < n) ? degd[i0 + 1] : 0;
    int v2 = (i0 + 2 < n) ? degd[i0 + 2] : 0;
    int v3 = (i0 + 3 < n) ? degd[i0 + 3] : 0;
    int T = v0 + v1 + v2 + v3;
    int lane = t & 63, wid = t >> 6;
    int s = T;
#pragma unroll
    for (int off = 1; off < 64; off <<= 1) {
        int u = __shfl_up(s, off);
        if (lane >= off) s += u;
    }
    if (lane == 63) wsum[wid] = s;
    __syncthreads();
    int wbase = 0;
    for (int w = 0; w < wid; ++w) wbase += wsum[w];
    int base = tbase[b] + wbase + (s - T);
    if (i0 + 0 < n) { int r = base;                 rowptr[i0 + 0] = r; cursor[i0 + 0] = r; }
    if (i0 + 1 < n) { int r = base + v0;            rowptr[i0 + 1] = r; cursor[i0 + 1] = r; }
    if (i0 + 2 < n) { int r = base + v0 + v1;       rowptr[i0 + 2] = r; cursor[i0 + 2] = r; }
    if (i0 + 3 < n) { int r = base + v0 + v1 + v2;  rowptr[i0 + 3] = r; cursor[i0 + 3] = r; }
}

// ---------------- CSR fill: cv[pos] = {src, norm} ----------------

__global__ void fill_kernel(const int* __restrict__ src, const int* __restrict__ dst,
                            const float* __restrict__ dinv, int* __restrict__ cursor,
                            int2* __restrict__ cv, int E) {
    int i = blockIdx.x * blockDim.x + threadIdx.x;
    int stride = gridDim.x * blockDim.x;
    for (; i < E; i += stride) {
        unsigned s = (unsigned)src[i];
        unsigned t = (unsigned)dst[i];
        if (s >= N_NODES || t >= N_NODES) continue;
        float v = -dinv[s] * dinv[t];
        int pos = atomicAdd(&cursor[t], 1);
        cv[pos] = make_int2((int)s, __float_as_int(v));
    }
}

// ---------------- propagate: out[i] = sum_e norm_e * h[src_e], CSR gather ----------------
// one wave per dst node, lane = feature index; 4-way unrolled accumulators

__global__ __launch_bounds__(256) void gather_kernel(const int* __restrict__ rowptr,
        const int2* __restrict__ cv, const float* __restrict__ h,
        float* __restrict__ out, int n) {
    int lane = threadIdx.x & 63;
    int wid = threadIdx.x >> 6;
    int node = blockIdx.x * 4 + wid;
    if (node >= n) return;
    int p = rowptr[node];
    const int pe = rowptr[node + 1];
    float a0 = 0.0f, a1 = 0.0f, a2 = 0.0f, a3 = 0.0f;
    for (; p + 3 < pe; p += 4) {
        int2 e0 = cv[p + 0];
        int2 e1 = cv[p + 1];
        int2 e2 = cv[p + 2];
        int2 e3 = cv[p + 3];
        a0 = fmaf(__int_as_float(e0.y), h[(size_t)e0.x * D + lane], a0);
        a1 = fmaf(__int_as_float(e1.y), h[(size_t)e1.x * D + lane], a1);
        a2 = fmaf(__int_as_float(e2.y), h[(size_t)e2.x * D + lane], a2);
        a3 = fmaf(__int_as_float(e3.y), h[(size_t)e3.x * D + lane], a3);
    }
    for (; p < pe; ++p) {
        int2 e0 = cv[p];
        a0 = fmaf(__int_as_float(e0.y), h[(size_t)e0.x * D + lane], a0);
    }
    out[(size_t)node * D + lane] = (a0 + a1) + (a2 + a3);
}

// ---------------- fused per-layer epilogue ----------------
// out[n,:] = relu( [Tx0 | Tx1 | 2*Tx2-Tx0] @ Wcat + b (+ skip) )

#define XSTRIDE 193

__global__ __launch_bounds__(256) void cheb_out_kernel(
        const float* __restrict__ inp, const float* __restrict__ t1,
        const float* __restrict__ t2, const float* __restrict__ W,
        const float* __restrict__ bias, float* __restrict__ out,
        int n, int addSkip) {
    __shared__ float sX[64 * XSTRIDE];
    const int t = threadIdx.x;
    const int lane = t & 63;
    const int jbase = __builtin_amdgcn_readfirstlane(((t >> 6) & 3) * 16);

    for (int tile = blockIdx.x; tile * 64 < n; tile += gridDim.x) {
        const int base = tile * 64;
        const int nNodes = min(64, n - base);

        __syncthreads();
#pragma unroll
        for (int a = 0; a < 4; ++a) {
            int idx = a * 256 + t;
            int node = idx >> 4;
            int c = (idx & 15) * 4;
            if (node < nNodes) {
                size_t g = (size_t)(base + node) * D + c;
                float4 i4 = *(const float4*)&inp[g];
                float4 a4 = *(const float4*)&t1[g];
                float4 b4 = *(const float4*)&t2[g];
                float* p = &sX[node * XSTRIDE + c];
                p[0] = i4.x; p[1] = i4.y; p[2] = i4.z; p[3] = i4.w;
                p[64] = a4.x; p[65] = a4.y; p[66] = a4.z; p[67] = a4.w;
                p[128] = fmaf(2.0f, b4.x, -i4.x);
                p[129] = fmaf(2.0f, b4.y, -i4.y);
                p[130] = fmaf(2.0f, b4.z, -i4.z);
                p[131] = fmaf(2.0f, b4.w, -i4.w);
            }
        }
        __syncthreads();

        float acc[16];
#pragma unroll
        for (int j = 0; j < 16; ++j) acc[j] = 0.0f;

        const float* __restrict__ xrow = &sX[lane * XSTRIDE];
#pragma unroll 4
        for (int r = 0; r < 3 * D; ++r) {
            float xv = xrow[r];
            const float* wr = W + (r << 6) + jbase;
#pragma unroll
            for (int j = 0; j < 16; ++j) acc[j] = fmaf(xv, wr[j], acc[j]);
        }

        if (lane < nNodes) {
            size_t ob = (size_t)(base + lane) * D + jbase;
#pragma unroll
            for (int j = 0; j < 16; ++j) {
                float o = acc[j] + bias[jbase + j];
                if (addSkip) o += xrow[jbase + j];
                out[ob + j] = fmaxf(o, 0.0f);
            }
        }
    }
}

extern "C" void kernel_launch(void* const* d_in, const int* in_sizes, int n_in,
                              void* d_out, int out_size, void* d_ws, size_t ws_size,
                              hipStream_t stream) {
    const float* x = (const float*)d_in[0];
    const int* ei = (const int*)d_in[1];
    const float* W = (const float*)d_in[2];   // [3,3,64,64]
    const float* b = (const float*)d_in[3];   // [3,64]
    float* out = (float*)d_out;

    const int* src = ei;             // edge_index[0]
    const int* dst = ei + N_EDGES;   // edge_index[1]

    const int nTilesScan = (N_NODES + SCAN_TILE - 1) / SCAN_TILE;   // 98

    char* w = (char*)d_ws;
    int*   degs   = (int*)w;                     w += (size_t)N_NODES * 4;
    int*   degd   = (int*)w;                     w += (size_t)N_NODES * 4;
    float* dinv   = (float*)w;                   w += (size_t)N_NODES * 4;
    int*   rowptr = (int*)w;                     w += (size_t)(N_NODES + 1) * 4;
    int*   cursor = (int*)w;                     w += (size_t)N_NODES * 4;
    int*   tsum   = (int*)w;                     w += (size_t)128 * 4;
    int2*  cv     = (int2*)w;                    w += (size_t)N_EDGES * 8;
    float* h      = (float*)w;                   w += (size_t)N_NODES * D * 4;
    float* t1     = (float*)w;                   w += (size_t)N_NODES * D * 4;
    float* t2     = (float*)w;                   w += (size_t)N_NODES * D * 4;

    // build CSR (by dst) + per-edge norm, once
    hipMemsetAsync(degs, 0, (size_t)N_NODES * 8, stream);   // degs+degd contiguous
    deg2_kernel<<<2048, 256, 0, stream>>>(src, dst, degs, degd, N_EDGES);
    dinv_kernel<<<(N_NODES + 255) / 256, 256, 0, stream>>>(degs, dinv, N_NODES);
    tile_sum_kernel<<<nTilesScan, 256, 0, stream>>>(degd, tsum, N_NODES);
    tscan_kernel<<<1, 64, 0, stream>>>(tsum, nTilesScan, rowptr + N_NODES);
    scan_kernel<<<nTilesScan, 256, 0, stream>>>(degd, tsum, rowptr, cursor, N_NODES);
    fill_kernel<<<2048, 256, 0, stream>>>(src, dst, dinv, cursor, cv, N_EDGES);

    const int gatherBlocks = (N_NODES + 3) / 4;          // wave per node
    const int nTilesOut = (N_NODES + 63) / 64;           // 1563

    const float* inp = x;
    for (int l = 0; l < NUM_LAYERS; ++l) {
        gather_kernel<<<gatherBlocks, 256, 0, stream>>>(rowptr, cv, inp, t1, N_NODES);
        gather_kernel<<<gatherBlocks, 256, 0, stream>>>(rowptr, cv, t1, t2, N_NODES);

        float* o = (l == NUM_LAYERS - 1) ? out : h;
        cheb_out_kernel<<<nTilesOut, 256, 0, stream>>>(
            inp, t1, t2, W + (size_t)l * 3 * D * D, b + (size_t)l * D, o,
            N_NODES, l > 0 ? 1 : 0);
        inp = h;
    }
}

// Round 4
// 646.815 us; speedup vs baseline: 5.3193x; 1.2766x over previous
//
#include <hip/hip_runtime.h>

#define N_NODES 100000
#define N_EDGES 1200000
#define D 64
#define NUM_LAYERS 3
#define SCAN_TILE 1024

typedef unsigned int uint;
typedef unsigned short u16;

static __device__ __forceinline__ float b2f(u16 u) {
    return __uint_as_float(((uint)u) << 16);
}
static __device__ __forceinline__ u16 f2b(float f) {
    uint u = __float_as_uint(f);
    return (u16)((u + 0x7FFFu + ((u >> 16) & 1u)) >> 16);
}

// ---------------- degree count (both directions) ----------------

__global__ void deg2_kernel(const int* __restrict__ src, const int* __restrict__ dst,
                            int* __restrict__ degs, int* __restrict__ degd, int E) {
    int i = blockIdx.x * blockDim.x + threadIdx.x;
    int stride = gridDim.x * blockDim.x;
    for (; i < E; i += stride) {
        unsigned s = (unsigned)src[i];
        unsigned t = (unsigned)dst[i];
        if (s < N_NODES) atomicAdd(&degs[s], 1);
        if (t < N_NODES) atomicAdd(&degd[t], 1);
    }
}

__global__ void dinv_kernel(const int* __restrict__ degs, float* __restrict__ dinv, int n) {
    int i = blockIdx.x * blockDim.x + threadIdx.x;
    if (i < n) {
        int d = degs[i];
        dinv[i] = (d > 0) ? rsqrtf((float)d) : 0.0f;
    }
}

// ---------------- exclusive scan of degd -> rowptr ----------------

__global__ __launch_bounds__(256) void tile_sum_kernel(const int* __restrict__ degd,
                                                       int* __restrict__ tsum, int n) {
    __shared__ int wsum[4];
    int b = blockIdx.x, t = threadIdx.x;
    int i0 = b * SCAN_TILE + t * 4;
    int s = 0;
#pragma unroll
    for (int k = 0; k < 4; ++k)
        if (i0 + k < n) s += degd[i0 + k];
#pragma unroll
    for (int off = 32; off > 0; off >>= 1) s += __shfl_down(s, off);
    int lane = t & 63, wid = t >> 6;
    if (lane == 0) wsum[wid] = s;
    __syncthreads();
    if (t == 0) tsum[b] = wsum[0] + wsum[1] + wsum[2] + wsum[3];
}

__global__ void tscan_kernel(int* __restrict__ tsum, int ntiles, int* __restrict__ rowptr_last) {
    if (blockIdx.x == 0 && threadIdx.x == 0) {
        int run = 0;
        for (int i = 0; i < ntiles; ++i) { int v = tsum[i]; tsum[i] = run; run += v; }
        rowptr_last[0] = run;
    }
}

__global__ __launch_bounds__(256) void scan_kernel(const int* __restrict__ degd,
        const int* __restrict__ tbase, int* __restrict__ rowptr,
        int* __restrict__ cursor, int n) {
    __shared__ int wsum[4];
    int b = blockIdx.x, t = threadIdx.x;
    int i0 = b * SCAN_TILE + t * 4;
    int v0 = (i0 + 0 < n) ? degd[i0 + 0] : 0;
    int v1 = (i0 + 1 < n) ? degd[i0 + 1] : 0;
    int v2 = (i0 + 2 < n) ? degd[i0 + 2] : 0;
    int v3 = (i0 + 3 < n) ? degd[i0 + 3] : 0;
    int T = v0 + v1 + v2 + v3;
    int lane = t & 63, wid = t >> 6;
    int s = T;
#pragma unroll
    for (int off = 1; off < 64; off <<= 1) {
        int u = __shfl_up(s, off);
        if (lane >= off) s += u;
    }
    if (lane == 63) wsum[wid] = s;
    __syncthreads();
    int wbase = 0;
    for (int w = 0; w < wid; ++w) wbase += wsum[w];
    int base = tbase[b] + wbase + (s - T);
    if (i0 + 0 < n) { int r = base;                 rowptr[i0 + 0] = r; cursor[i0 + 0] = r; }
    if (i0 + 1 < n) { int r = base + v0;            rowptr[i0 + 1] = r; cursor[i0 + 1] = r; }
    if (i0 + 2 < n) { int r = base + v0 + v1;       rowptr[i0 + 2] = r; cursor[i0 + 2] = r; }
    if (i0 + 3 < n) { int r = base + v0 + v1 + v2;  rowptr[i0 + 3] = r; cursor[i0 + 3] = r; }
}

// ---------------- CSR fill: cv[pos] = src (norm folded into features) ----------------

__global__ void fill_kernel(const int* __restrict__ src, const int* __restrict__ dst,
                            int* __restrict__ cursor, int* __restrict__ cv, int E) {
    int i = blockIdx.x * blockDim.x + threadIdx.x;
    int stride = gridDim.x * blockDim.x;
    for (; i < E; i += stride) {
        unsigned s = (unsigned)src[i];
        unsigned t = (unsigned)dst[i];
        if (s >= N_NODES || t >= N_NODES) continue;
        int pos = atomicAdd(&cursor[t], 1);
        cv[pos] = (int)s;
    }
}

// ---------------- x -> gx = dinv * x (bf16) ----------------

__global__ __launch_bounds__(256) void cvt_kernel(const float* __restrict__ x,
        const float* __restrict__ dinv, u16* __restrict__ gx, int nvec) {
    int i = blockIdx.x * blockDim.x + threadIdx.x;
    if (i >= nvec) return;
    float4 v = ((const float4*)x)[i];
    float dv = dinv[i >> 4];   // (i*4)/64
    uint2 b;
    b.x = (uint)f2b(v.x * dv) | ((uint)f2b(v.y * dv) << 16);
    b.y = (uint)f2b(v.z * dv) | ((uint)f2b(v.w * dv) << 16);
    ((uint2*)gx)[i] = b;
}

// ---------------- propagate: out[i] = -dinv[i] * sum_e g[src_e]  (g pre-scaled) --------
// one wave per dst node, lane = feature; scalarized CSR walk

__global__ __launch_bounds__(256) void gather_kernel(const int* __restrict__ rowptr,
        const int* __restrict__ cv, const u16* __restrict__ g,
        const float* __restrict__ dinv, u16* __restrict__ outp,
        u16* __restrict__ outscaled, int n) {
    int lane = threadIdx.x & 63;
    int node = __builtin_amdgcn_readfirstlane(blockIdx.x * 4 + (threadIdx.x >> 6));
    if (node >= n) return;
    int p = rowptr[node];
    const int pe = rowptr[node + 1];
    float a0 = 0.0f, a1 = 0.0f, a2 = 0.0f, a3 = 0.0f;
    for (; p + 3 < pe; p += 4) {
        int s0 = cv[p + 0];
        int s1 = cv[p + 1];
        int s2 = cv[p + 2];
        int s3 = cv[p + 3];
        a0 += b2f(g[(size_t)s0 * D + lane]);
        a1 += b2f(g[(size_t)s1 * D + lane]);
        a2 += b2f(g[(size_t)s2 * D + lane]);
        a3 += b2f(g[(size_t)s3 * D + lane]);
    }
    for (; p < pe; ++p) {
        int s0 = cv[p];
        a0 += b2f(g[(size_t)s0 * D + lane]);
    }
    float dv = dinv[node];
    float v = -dv * ((a0 + a1) + (a2 + a3));
    size_t ob = (size_t)node * D + lane;
    outp[ob] = f2b(v);
    if (outscaled) outscaled[ob] = f2b(dv * v);
}

// ---------------- fused per-layer epilogue ----------------
// out[n,:] = relu( [Tx0 | Tx1 | 2*Tx2-Tx0] @ Wcat + b (+ skip) )

#define XSTRIDE 193

__global__ __launch_bounds__(256) void cheb_out_kernel(
        const u16* __restrict__ inp_b, const float* __restrict__ inp_f,
        const u16* __restrict__ t1, const u16* __restrict__ t2,
        const float* __restrict__ W, const float* __restrict__ bias,
        const float* __restrict__ dinv,
        u16* __restrict__ outb, u16* __restrict__ goutb, float* __restrict__ outf,
        int n, int addSkip, int writeScaled, int outF32, int inpF32) {
    __shared__ float sX[64 * XSTRIDE];
    const int t = threadIdx.x;
    const int lane = t & 63;
    const int jbase = __builtin_amdgcn_readfirstlane(((t >> 6) & 3) * 16);

    for (int tile = blockIdx.x; tile * 64 < n; tile += gridDim.x) {
        const int base = tile * 64;
        const int nNodes = min(64, n - base);

        __syncthreads();
#pragma unroll
        for (int a = 0; a < 2; ++a) {
            int idx = a * 256 + t;        // 0..511
            int node = idx >> 3;          // 0..63
            int c = (idx & 7) * 8;        // 0..56
            if (node < nNodes) {
                size_t off = (size_t)(base + node) * D + c;
                float fi[8], f1v[8], f2v[8];
                if (inpF32) {
                    float4 va = *(const float4*)(inp_f + off);
                    float4 vb = *(const float4*)(inp_f + off + 4);
                    fi[0] = va.x; fi[1] = va.y; fi[2] = va.z; fi[3] = va.w;
                    fi[4] = vb.x; fi[5] = vb.y; fi[6] = vb.z; fi[7] = vb.w;
                } else {
                    uint4 vi = *(const uint4*)(inp_b + off);
                    const uint* u = (const uint*)&vi;
#pragma unroll
                    for (int k = 0; k < 4; ++k) {
                        fi[2 * k]     = __uint_as_float(u[k] << 16);
                        fi[2 * k + 1] = __uint_as_float(u[k] & 0xFFFF0000u);
                    }
                }
                uint4 v1 = *(const uint4*)(t1 + off);
                uint4 v2 = *(const uint4*)(t2 + off);
                const uint* u1 = (const uint*)&v1;
                const uint* u2 = (const uint*)&v2;
#pragma unroll
                for (int k = 0; k < 4; ++k) {
                    f1v[2 * k]     = __uint_as_float(u1[k] << 16);
                    f1v[2 * k + 1] = __uint_as_float(u1[k] & 0xFFFF0000u);
                    f2v[2 * k]     = __uint_as_float(u2[k] << 16);
                    f2v[2 * k + 1] = __uint_as_float(u2[k] & 0xFFFF0000u);
                }
                float* p = &sX[node * XSTRIDE + c];
#pragma unroll
                for (int k = 0; k < 8; ++k) {
                    p[k]       = fi[k];
                    p[64 + k]  = f1v[k];
                    p[128 + k] = fmaf(2.0f, f2v[k], -fi[k]);
                }
            }
        }
        __syncthreads();

        float acc[16];
#pragma unroll
        for (int j = 0; j < 16; ++j) acc[j] = 0.0f;

        const float* __restrict__ xrow = &sX[lane * XSTRIDE];
#pragma unroll 4
        for (int r = 0; r < 3 * D; ++r) {
            float xv = xrow[r];
            const float* wr = W + (r << 6) + jbase;   // wave-uniform -> s_load
#pragma unroll
            for (int j = 0; j < 16; ++j) acc[j] = fmaf(xv, wr[j], acc[j]);
        }

        if (lane < nNodes) {
            size_t ob = (size_t)(base + lane) * D + jbase;
            float o[16];
#pragma unroll
            for (int j = 0; j < 16; ++j) {
                float v = acc[j] + bias[jbase + j];
                if (addSkip) v += xrow[jbase + j];
                o[j] = fmaxf(v, 0.0f);
            }
            if (outF32) {
#pragma unroll
                for (int q = 0; q < 4; ++q) {
                    float4 v4 = make_float4(o[4 * q], o[4 * q + 1], o[4 * q + 2], o[4 * q + 3]);
                    *(float4*)(outf + ob + 4 * q) = v4;
                }
            } else {
                uint w[8];
#pragma unroll
                for (int k = 0; k < 8; ++k)
                    w[k] = (uint)f2b(o[2 * k]) | ((uint)f2b(o[2 * k + 1]) << 16);
                *(uint4*)(outb + ob)     = make_uint4(w[0], w[1], w[2], w[3]);
                *(uint4*)(outb + ob + 8) = make_uint4(w[4], w[5], w[6], w[7]);
                if (writeScaled) {
                    float dv = dinv[base + lane];
                    uint g[8];
#pragma unroll
                    for (int k = 0; k < 8; ++k)
                        g[k] = (uint)f2b(o[2 * k] * dv) | ((uint)f2b(o[2 * k + 1] * dv) << 16);
                    *(uint4*)(goutb + ob)     = make_uint4(g[0], g[1], g[2], g[3]);
                    *(uint4*)(goutb + ob + 8) = make_uint4(g[4], g[5], g[6], g[7]);
                }
            }
        }
    }
}

extern "C" void kernel_launch(void* const* d_in, const int* in_sizes, int n_in,
                              void* d_out, int out_size, void* d_ws, size_t ws_size,
                              hipStream_t stream) {
    const float* x = (const float*)d_in[0];
    const int* ei = (const int*)d_in[1];
    const float* W = (const float*)d_in[2];   // [3,3,64,64]
    const float* b = (const float*)d_in[3];   // [3,64]
    float* out = (float*)d_out;

    const int* src = ei;             // edge_index[0]
    const int* dst = ei + N_EDGES;   // edge_index[1]

    const int nTilesScan = (N_NODES + SCAN_TILE - 1) / SCAN_TILE;   // 98
    const size_t ND = (size_t)N_NODES * D;

    char* w = (char*)d_ws;
    int*   degs   = (int*)w;        w += (size_t)N_NODES * 4;
    int*   degd   = (int*)w;        w += (size_t)N_NODES * 4;
    float* dinv   = (float*)w;      w += (size_t)N_NODES * 4;
    int*   rowptr = (int*)w;        w += (size_t)(N_NODES + 4) * 4;
    int*   cursor = (int*)w;        w += (size_t)N_NODES * 4;
    int*   tsum   = (int*)w;        w += (size_t)128 * 4;
    int*   cv     = (int*)w;        w += (size_t)N_EDGES * 4;
    u16*   gx     = (u16*)w;        w += ND * 2;
    u16*   h      = (u16*)w;        w += ND * 2;
    u16*   gh     = (u16*)w;        w += ND * 2;
    u16*   t1     = (u16*)w;        w += ND * 2;
    u16*   gt1    = (u16*)w;        w += ND * 2;
    u16*   t2     = (u16*)w;        w += ND * 2;

    // build CSR (by dst) + dinv, once
    hipMemsetAsync(degs, 0, (size_t)N_NODES * 8, stream);   // degs+degd contiguous
    deg2_kernel<<<2048, 256, 0, stream>>>(src, dst, degs, degd, N_EDGES);
    dinv_kernel<<<(N_NODES + 255) / 256, 256, 0, stream>>>(degs, dinv, N_NODES);
    tile_sum_kernel<<<nTilesScan, 256, 0, stream>>>(degd, tsum, N_NODES);
    tscan_kernel<<<1, 64, 0, stream>>>(tsum, nTilesScan, rowptr + N_NODES);
    scan_kernel<<<nTilesScan, 256, 0, stream>>>(degd, tsum, rowptr, cursor, N_NODES);
    fill_kernel<<<2048, 256, 0, stream>>>(src, dst, cursor, cv, N_EDGES);
    cvt_kernel<<<(int)((ND / 4 + 255) / 256), 256, 0, stream>>>(x, dinv, gx, (int)(ND / 4));

    const int gatherBlocks = (N_NODES + 3) / 4;
    const int nTilesOut = (N_NODES + 63) / 64;

    for (int l = 0; l < NUM_LAYERS; ++l) {
        const u16* gin = (l == 0) ? gx : gh;
        gather_kernel<<<gatherBlocks, 256, 0, stream>>>(rowptr, cv, gin, dinv, t1, gt1, N_NODES);
        gather_kernel<<<gatherBlocks, 256, 0, stream>>>(rowptr, cv, gt1, dinv, t2, (u16*)0, N_NODES);

        int last = (l == NUM_LAYERS - 1);
        cheb_out_kernel<<<nTilesOut, 256, 0, stream>>>(
            h, x, t1, t2, W + (size_t)l * 3 * D * D, b + (size_t)l * D, dinv,
            h, gh, out, N_NODES,
            /*addSkip=*/l > 0, /*writeScaled=*/!last, /*outF32=*/last, /*inpF32=*/l == 0);
    }
}

// Round 5
// 526.018 us; speedup vs baseline: 6.5409x; 1.2296x over previous
//
#include <hip/hip_runtime.h>

#define N_NODES 100000
#define N_EDGES 1200000
#define D 64
#define NUM_LAYERS 3

#define NB 196          // coarse buckets
#define BSZ 512         // nodes per bucket (NB*BSZ = 100352 >= N_NODES)
#define CHUNK 4096      // edges per partition block
#define NCHUNK ((N_EDGES + CHUNK - 1) / CHUNK)   // 293

typedef unsigned int uint;
typedef unsigned short u16;

static __device__ __forceinline__ float b2f(u16 u) {
    return __uint_as_float(((uint)u) << 16);
}
static __device__ __forceinline__ u16 f2b(float f) {
    uint u = __float_as_uint(f);
    return (u16)((u + 0x7FFFu + ((u >> 16) & 1u)) >> 16);
}

// ---- P1: coarse bucket histograms (dst and src) via LDS ----
__global__ __launch_bounds__(256) void hist_kernel(const int* __restrict__ src,
        const int* __restrict__ dst, int* __restrict__ cnt2, int E) {
    __shared__ int hD[NB], hS[NB];
    for (int i = threadIdx.x; i < NB; i += 256) { hD[i] = 0; hS[i] = 0; }
    __syncthreads();
    int i = blockIdx.x * 256 + threadIdx.x;
    int stride = gridDim.x * 256;
    for (; i < E; i += stride) {
        atomicAdd(&hD[((unsigned)dst[i]) >> 9], 1);
        atomicAdd(&hS[((unsigned)src[i]) >> 9], 1);
    }
    __syncthreads();
    for (int i2 = threadIdx.x; i2 < NB; i2 += 256) {
        if (hD[i2]) atomicAdd(&cnt2[i2], hD[i2]);
        if (hS[i2]) atomicAdd(&cnt2[NB + i2], hS[i2]);
    }
}

// ---- P2a: scan bucket counts -> bases + cursors ----
__global__ __launch_bounds__(256) void scanb_kernel(const int* __restrict__ cnt2,
        int* __restrict__ base2, int* __restrict__ curs2) {
    __shared__ int buf[256];
    int t = threadIdx.x;
    for (int arr = 0; arr < 2; ++arr) {
        int v = (t < NB) ? cnt2[arr * NB + t] : 0;
        buf[t] = v;
        __syncthreads();
        for (int off = 1; off < 256; off <<= 1) {
            int u = (t >= off) ? buf[t - off] : 0;
            __syncthreads();
            buf[t] += u;
            __syncthreads();
        }
        int excl = buf[t] - v;
        if (t < NB) {
            base2[arr * (NB + 1) + t] = excl;
            curs2[arr * NB + t] = excl;
        }
        if (t == NB - 1) base2[arr * (NB + 1) + NB] = buf[t];
        __syncthreads();
    }
}

// ---- P2b: partition edges into coarse buckets (LDS-staged chunks) ----
__global__ __launch_bounds__(256) void part_kernel(const int* __restrict__ src,
        const int* __restrict__ dst, int* __restrict__ cursD, int* __restrict__ cursS,
        int* __restrict__ dstPart, u16* __restrict__ srcPart, int E) {
    __shared__ int eS[CHUNK], eT[CHUNK];
    __shared__ int hD[NB], hS[NB], bD[NB], bS[NB];
    int e0 = blockIdx.x * CHUNK;
    int n = min(CHUNK, E - e0);
    for (int i = threadIdx.x; i < NB; i += 256) { hD[i] = 0; hS[i] = 0; }
    for (int i = threadIdx.x; i < n; i += 256) { eS[i] = src[e0 + i]; eT[i] = dst[e0 + i]; }
    __syncthreads();
    for (int i = threadIdx.x; i < n; i += 256) {
        atomicAdd(&hD[((unsigned)eT[i]) >> 9], 1);
        atomicAdd(&hS[((unsigned)eS[i]) >> 9], 1);
    }
    __syncthreads();
    for (int i = threadIdx.x; i < NB; i += 256) {
        bD[i] = hD[i] ? atomicAdd(&cursD[i], hD[i]) : 0;
        bS[i] = hS[i] ? atomicAdd(&cursS[i], hS[i]) : 0;
        hD[i] = 0; hS[i] = 0;          // reuse as local cursors
    }
    __syncthreads();
    for (int i = threadIdx.x; i < n; i += 256) {
        int s = eS[i], t = eT[i];
        int kb = ((unsigned)t) >> 9;
        int pos = bD[kb] + atomicAdd(&hD[kb], 1);
        dstPart[pos] = ((t & 511) << 20) | s;
        kb = ((unsigned)s) >> 9;
        pos = bS[kb] + atomicAdd(&hS[kb], 1);
        srcPart[pos] = (u16)(s & 511);
    }
}

// ---- P3a: per-bucket CSR (rowptr + cv) entirely in LDS ----
__global__ __launch_bounds__(256) void csr_kernel(const int* __restrict__ baseD,
        const int* __restrict__ dstPart, int* __restrict__ rowptr, int* __restrict__ cv) {
    __shared__ int cnt[BSZ], curs[BSZ], psum[256];
    int b = blockIdx.x, t = threadIdx.x;
    int node0 = b * BSZ;
    int eb = baseD[b], ee = baseD[b + 1];
    for (int i = t; i < BSZ; i += 256) cnt[i] = 0;
    __syncthreads();
    for (int e = eb + t; e < ee; e += 256)
        atomicAdd(&cnt[((unsigned)dstPart[e]) >> 20], 1);
    __syncthreads();
    int c0 = cnt[2 * t], c1 = cnt[2 * t + 1];
    psum[t] = c0 + c1;
    __syncthreads();
    for (int off = 1; off < 256; off <<= 1) {
        int u = (t >= off) ? psum[t - off] : 0;
        __syncthreads();
        psum[t] += u;
        __syncthreads();
    }
    int excl = psum[t] - c0 - c1;
    curs[2 * t] = excl;
    curs[2 * t + 1] = excl + c0;
    // rowptr (before cursors are mutated)
    int n0 = node0 + 2 * t;
    if (n0 < N_NODES)     rowptr[n0]     = eb + excl;
    if (n0 + 1 < N_NODES) rowptr[n0 + 1] = eb + excl + c0;
    if (b == gridDim.x - 1 && t == 0) rowptr[N_NODES] = ee;
    __syncthreads();
    for (int e = eb + t; e < ee; e += 256) {
        int p = dstPart[e];
        int loc = ((unsigned)p) >> 20;
        int pos = eb + atomicAdd(&curs[loc], 1);
        cv[pos] = p & 0xFFFFF;
    }
}

// ---- P3b: per-bucket src-degree histogram -> dinv ----
__global__ __launch_bounds__(256) void degs_kernel(const int* __restrict__ baseS,
        const u16* __restrict__ srcPart, float* __restrict__ dinv) {
    __shared__ int cnt[BSZ];
    int b = blockIdx.x, t = threadIdx.x;
    int eb = baseS[b], ee = baseS[b + 1];
    for (int i = t; i < BSZ; i += 256) cnt[i] = 0;
    __syncthreads();
    for (int e = eb + t; e < ee; e += 256)
        atomicAdd(&cnt[srcPart[e]], 1);
    __syncthreads();
    for (int i = t; i < BSZ; i += 256) {
        int node = b * BSZ + i;
        if (node < N_NODES) {
            int d = cnt[i];
            dinv[node] = (d > 0) ? rsqrtf((float)d) : 0.0f;
        }
    }
}

// ---- x -> gx = dinv * x (bf16) ----
__global__ __launch_bounds__(256) void cvt_kernel(const float* __restrict__ x,
        const float* __restrict__ dinv, u16* __restrict__ gx, int nvec) {
    int i = blockIdx.x * blockDim.x + threadIdx.x;
    if (i >= nvec) return;
    float4 v = ((const float4*)x)[i];
    float dv = dinv[i >> 4];
    uint2 b;
    b.x = (uint)f2b(v.x * dv) | ((uint)f2b(v.y * dv) << 16);
    b.y = (uint)f2b(v.z * dv) | ((uint)f2b(v.w * dv) << 16);
    ((uint2*)gx)[i] = b;
}

// ---- propagate: out[i] = -dinv[i] * sum_e g[src_e] (g pre-scaled by dinv) ----
__global__ __launch_bounds__(256) void gather_kernel(const int* __restrict__ rowptr,
        const int* __restrict__ cv, const u16* __restrict__ g,
        const float* __restrict__ dinv, u16* __restrict__ outp,
        u16* __restrict__ outscaled, int n) {
    int lane = threadIdx.x & 63;
    int node = __builtin_amdgcn_readfirstlane(blockIdx.x * 4 + (threadIdx.x >> 6));
    if (node >= n) return;
    int p = rowptr[node];
    const int pe = rowptr[node + 1];
    float a0 = 0.0f, a1 = 0.0f, a2 = 0.0f, a3 = 0.0f;
    for (; p + 3 < pe; p += 4) {
        int s0 = cv[p + 0];
        int s1 = cv[p + 1];
        int s2 = cv[p + 2];
        int s3 = cv[p + 3];
        a0 += b2f(g[(size_t)s0 * D + lane]);
        a1 += b2f(g[(size_t)s1 * D + lane]);
        a2 += b2f(g[(size_t)s2 * D + lane]);
        a3 += b2f(g[(size_t)s3 * D + lane]);
    }
    for (; p < pe; ++p)
        a0 += b2f(g[(size_t)cv[p] * D + lane]);
    float dv = dinv[node];
    float v = -dv * ((a0 + a1) + (a2 + a3));
    size_t ob = (size_t)node * D + lane;
    outp[ob] = f2b(v);
    if (outscaled) outscaled[ob] = f2b(dv * v);
}

// ---- fused per-layer epilogue ----
#define XSTRIDE 193

__global__ __launch_bounds__(256) void cheb_out_kernel(
        const u16* __restrict__ inp_b, const float* __restrict__ inp_f,
        const u16* __restrict__ t1, const u16* __restrict__ t2,
        const float* __restrict__ W, const float* __restrict__ bias,
        const float* __restrict__ dinv,
        u16* __restrict__ outb, u16* __restrict__ goutb, float* __restrict__ outf,
        int n, int addSkip, int writeScaled, int outF32, int inpF32) {
    __shared__ float sX[64 * XSTRIDE];
    const int t = threadIdx.x;
    const int lane = t & 63;
    const int jbase = __builtin_amdgcn_readfirstlane(((t >> 6) & 3) * 16);

    for (int tile = blockIdx.x; tile * 64 < n; tile += gridDim.x) {
        const int base = tile * 64;
        const int nNodes = min(64, n - base);

        __syncthreads();
#pragma unroll
        for (int a = 0; a < 2; ++a) {
            int idx = a * 256 + t;
            int node = idx >> 3;
            int c = (idx & 7) * 8;
            if (node < nNodes) {
                size_t off = (size_t)(base + node) * D + c;
                float fi[8], f1v[8], f2v[8];
                if (inpF32) {
                    float4 va = *(const float4*)(inp_f + off);
                    float4 vb = *(const float4*)(inp_f + off + 4);
                    fi[0] = va.x; fi[1] = va.y; fi[2] = va.z; fi[3] = va.w;
                    fi[4] = vb.x; fi[5] = vb.y; fi[6] = vb.z; fi[7] = vb.w;
                } else {
                    uint4 vi = *(const uint4*)(inp_b + off);
                    const uint* u = (const uint*)&vi;
#pragma unroll
                    for (int k = 0; k < 4; ++k) {
                        fi[2 * k]     = __uint_as_float(u[k] << 16);
                        fi[2 * k + 1] = __uint_as_float(u[k] & 0xFFFF0000u);
                    }
                }
                uint4 v1 = *(const uint4*)(t1 + off);
                uint4 v2 = *(const uint4*)(t2 + off);
                const uint* u1 = (const uint*)&v1;
                const uint* u2 = (const uint*)&v2;
#pragma unroll
                for (int k = 0; k < 4; ++k) {
                    f1v[2 * k]     = __uint_as_float(u1[k] << 16);
                    f1v[2 * k + 1] = __uint_as_float(u1[k] & 0xFFFF0000u);
                    f2v[2 * k]     = __uint_as_float(u2[k] << 16);
                    f2v[2 * k + 1] = __uint_as_float(u2[k] & 0xFFFF0000u);
                }
                float* p = &sX[node * XSTRIDE + c];
#pragma unroll
                for (int k = 0; k < 8; ++k) {
                    p[k]       = fi[k];
                    p[64 + k]  = f1v[k];
                    p[128 + k] = fmaf(2.0f, f2v[k], -fi[k]);
                }
            }
        }
        __syncthreads();

        float acc[16];
#pragma unroll
        for (int j = 0; j < 16; ++j) acc[j] = 0.0f;

        const float* __restrict__ xrow = &sX[lane * XSTRIDE];
#pragma unroll 4
        for (int r = 0; r < 3 * D; ++r) {
            float xv = xrow[r];
            const float* wr = W + (r << 6) + jbase;   // wave-uniform -> s_load
#pragma unroll
            for (int j = 0; j < 16; ++j) acc[j] = fmaf(xv, wr[j], acc[j]);
        }

        if (lane < nNodes) {
            size_t ob = (size_t)(base + lane) * D + jbase;
            float o[16];
#pragma unroll
            for (int j = 0; j < 16; ++j) {
                float v = acc[j] + bias[jbase + j];
                if (addSkip) v += xrow[jbase + j];
                o[j] = fmaxf(v, 0.0f);
            }
            if (outF32) {
#pragma unroll
                for (int q = 0; q < 4; ++q)
                    *(float4*)(outf + ob + 4 * q) =
                        make_float4(o[4 * q], o[4 * q + 1], o[4 * q + 2], o[4 * q + 3]);
            } else {
                uint w[8];
#pragma unroll
                for (int k = 0; k < 8; ++k)
                    w[k] = (uint)f2b(o[2 * k]) | ((uint)f2b(o[2 * k + 1]) << 16);
                *(uint4*)(outb + ob)     = make_uint4(w[0], w[1], w[2], w[3]);
                *(uint4*)(outb + ob + 8) = make_uint4(w[4], w[5], w[6], w[7]);
                if (writeScaled) {
                    float dv = dinv[base + lane];
                    uint g[8];
#pragma unroll
                    for (int k = 0; k < 8; ++k)
                        g[k] = (uint)f2b(o[2 * k] * dv) | ((uint)f2b(o[2 * k + 1] * dv) << 16);
                    *(uint4*)(goutb + ob)     = make_uint4(g[0], g[1], g[2], g[3]);
                    *(uint4*)(goutb + ob + 8) = make_uint4(g[4], g[5], g[6], g[7]);
                }
            }
        }
    }
}

extern "C" void kernel_launch(void* const* d_in, const int* in_sizes, int n_in,
                              void* d_out, int out_size, void* d_ws, size_t ws_size,
                              hipStream_t stream) {
    const float* x = (const float*)d_in[0];
    const int* ei = (const int*)d_in[1];
    const float* W = (const float*)d_in[2];   // [3,3,64,64]
    const float* b = (const float*)d_in[3];   // [3,64]
    float* out = (float*)d_out;

    const int* src = ei;
    const int* dst = ei + N_EDGES;

    const size_t ND = (size_t)N_NODES * D;

    char* w = (char*)d_ws;
    int*   cnt2   = (int*)w;        w += (size_t)(2 * NB) * 4;
    int*   base2  = (int*)w;        w += (size_t)(2 * (NB + 1)) * 4;
    int*   curs2  = (int*)w;        w += (size_t)(2 * NB) * 4;
    int*   rowptr = (int*)w;        w += (size_t)(N_NODES + 4) * 4;
    float* dinv   = (float*)w;      w += (size_t)N_NODES * 4;
    int*   cv     = (int*)w;        w += (size_t)N_EDGES * 4;
    u16*   gx     = (u16*)w;        w += ND * 2;
    u16*   h      = (u16*)w;        w += ND * 2;
    u16*   gh     = (u16*)w;        w += ND * 2;
    u16*   t1     = (u16*)w;        w += ND * 2;
    u16*   gt1    = (u16*)w;        w += ND * 2;
    u16*   t2     = (u16*)w;        w += ND * 2;
    // partition buffers alias gt1/t2 (both first written by gathers, after CSR build)
    int*   dstPart = (int*)gt1;     // 4.8 MB <= 12.8 MB
    u16*   srcPart = (u16*)t2;      // 2.4 MB <= 12.8 MB

    int* baseD = base2;
    int* baseS = base2 + (NB + 1);
    int* cursD = curs2;
    int* cursS = curs2 + NB;

    // ---- CSR build (bucketed radix partition, LDS atomics) ----
    hipMemsetAsync(cnt2, 0, (size_t)(2 * NB) * 4, stream);
    hist_kernel<<<304, 256, 0, stream>>>(src, dst, cnt2, N_EDGES);
    scanb_kernel<<<1, 256, 0, stream>>>(cnt2, base2, curs2);
    part_kernel<<<NCHUNK, 256, 0, stream>>>(src, dst, cursD, cursS, dstPart, srcPart, N_EDGES);
    csr_kernel<<<NB, 256, 0, stream>>>(baseD, dstPart, rowptr, cv);
    degs_kernel<<<NB, 256, 0, stream>>>(baseS, srcPart, dinv);
    cvt_kernel<<<(int)((ND / 4 + 255) / 256), 256, 0, stream>>>(x, dinv, gx, (int)(ND / 4));

    const int gatherBlocks = (N_NODES + 3) / 4;
    const int nTilesOut = (N_NODES + 63) / 64;

    for (int l = 0; l < NUM_LAYERS; ++l) {
        const u16* gin = (l == 0) ? gx : gh;
        gather_kernel<<<gatherBlocks, 256, 0, stream>>>(rowptr, cv, gin, dinv, t1, gt1, N_NODES);
        gather_kernel<<<gatherBlocks, 256, 0, stream>>>(rowptr, cv, gt1, dinv, t2, (u16*)0, N_NODES);

        int last = (l == NUM_LAYERS - 1);
        cheb_out_kernel<<<nTilesOut, 256, 0, stream>>>(
            h, x, t1, t2, W + (size_t)l * 3 * D * D, b + (size_t)l * D, dinv,
            h, gh, out, N_NODES,
            /*addSkip=*/l > 0, /*writeScaled=*/!last, /*outF32=*/last, /*inpF32=*/l == 0);
    }
}

// Round 6
// 463.707 us; speedup vs baseline: 7.4198x; 1.1344x over previous
//
#include <hip/hip_runtime.h>

#define N_NODES 100000
#define N_EDGES 1200000
#define D 64
#define NUM_LAYERS 3

#define NB 196          // coarse buckets
#define BSZ 512         // nodes per bucket (NB*BSZ = 100352 >= N_NODES)
#define NPAD (NB * BSZ) // padded node count (100352, multiple of 64)
#define CHUNK 4096      // edges per partition block
#define NCHUNK ((N_EDGES + CHUNK - 1) / CHUNK)   // 293

typedef unsigned int uint;
typedef unsigned short u16;

using short8 = __attribute__((ext_vector_type(8))) short;
using f32x4  = __attribute__((ext_vector_type(4))) float;

static __device__ __forceinline__ float b2f(u16 u) {
    return __uint_as_float(((uint)u) << 16);
}
static __device__ __forceinline__ u16 f2b(float f) {
    uint u = __float_as_uint(f);
    return (u16)((u + 0x7FFFu + ((u >> 16) & 1u)) >> 16);
}

// ---- P1: coarse bucket histograms (dst and src) via LDS ----
__global__ __launch_bounds__(256) void hist_kernel(const int* __restrict__ src,
        const int* __restrict__ dst, int* __restrict__ cnt2, int E) {
    __shared__ int hD[NB], hS[NB];
    for (int i = threadIdx.x; i < NB; i += 256) { hD[i] = 0; hS[i] = 0; }
    __syncthreads();
    int i = blockIdx.x * 256 + threadIdx.x;
    int stride = gridDim.x * 256;
    for (; i < E; i += stride) {
        atomicAdd(&hD[((unsigned)dst[i]) >> 9], 1);
        atomicAdd(&hS[((unsigned)src[i]) >> 9], 1);
    }
    __syncthreads();
    for (int i2 = threadIdx.x; i2 < NB; i2 += 256) {
        if (hD[i2]) atomicAdd(&cnt2[i2], hD[i2]);
        if (hS[i2]) atomicAdd(&cnt2[NB + i2], hS[i2]);
    }
}

// ---- P2a: scan bucket counts -> bases + cursors ----
__global__ __launch_bounds__(256) void scanb_kernel(const int* __restrict__ cnt2,
        int* __restrict__ base2, int* __restrict__ curs2) {
    __shared__ int buf[256];
    int t = threadIdx.x;
    for (int arr = 0; arr < 2; ++arr) {
        int v = (t < NB) ? cnt2[arr * NB + t] : 0;
        buf[t] = v;
        __syncthreads();
        for (int off = 1; off < 256; off <<= 1) {
            int u = (t >= off) ? buf[t - off] : 0;
            __syncthreads();
            buf[t] += u;
            __syncthreads();
        }
        int excl = buf[t] - v;
        if (t < NB) {
            base2[arr * (NB + 1) + t] = excl;
            curs2[arr * NB + t] = excl;
        }
        if (t == NB - 1) base2[arr * (NB + 1) + NB] = buf[t];
        __syncthreads();
    }
}

// ---- P2b: partition edges into coarse buckets (LDS-staged chunks) ----
__global__ __launch_bounds__(256) void part_kernel(const int* __restrict__ src,
        const int* __restrict__ dst, int* __restrict__ cursD, int* __restrict__ cursS,
        int* __restrict__ dstPart, u16* __restrict__ srcPart, int E) {
    __shared__ int eS[CHUNK], eT[CHUNK];
    __shared__ int hD[NB], hS[NB], bD[NB], bS[NB];
    int e0 = blockIdx.x * CHUNK;
    int n = min(CHUNK, E - e0);
    for (int i = threadIdx.x; i < NB; i += 256) { hD[i] = 0; hS[i] = 0; }
    for (int i = threadIdx.x; i < n; i += 256) { eS[i] = src[e0 + i]; eT[i] = dst[e0 + i]; }
    __syncthreads();
    for (int i = threadIdx.x; i < n; i += 256) {
        atomicAdd(&hD[((unsigned)eT[i]) >> 9], 1);
        atomicAdd(&hS[((unsigned)eS[i]) >> 9], 1);
    }
    __syncthreads();
    for (int i = threadIdx.x; i < NB; i += 256) {
        bD[i] = hD[i] ? atomicAdd(&cursD[i], hD[i]) : 0;
        bS[i] = hS[i] ? atomicAdd(&cursS[i], hS[i]) : 0;
        hD[i] = 0; hS[i] = 0;          // reuse as local cursors
    }
    __syncthreads();
    for (int i = threadIdx.x; i < n; i += 256) {
        int s = eS[i], t = eT[i];
        int kb = ((unsigned)t) >> 9;
        int pos = bD[kb] + atomicAdd(&hD[kb], 1);
        dstPart[pos] = ((t & 511) << 20) | s;
        kb = ((unsigned)s) >> 9;
        pos = bS[kb] + atomicAdd(&hS[kb], 1);
        srcPart[pos] = (u16)(s & 511);
    }
}

// ---- P3a: per-bucket CSR (rowptr + cv) entirely in LDS ----
__global__ __launch_bounds__(256) void csr_kernel(const int* __restrict__ baseD,
        const int* __restrict__ dstPart, int* __restrict__ rowptr, int* __restrict__ cv) {
    __shared__ int cnt[BSZ], curs[BSZ], psum[256];
    int b = blockIdx.x, t = threadIdx.x;
    int node0 = b * BSZ;
    int eb = baseD[b], ee = baseD[b + 1];
    for (int i = t; i < BSZ; i += 256) cnt[i] = 0;
    __syncthreads();
    for (int e = eb + t; e < ee; e += 256)
        atomicAdd(&cnt[((unsigned)dstPart[e]) >> 20], 1);
    __syncthreads();
    int c0 = cnt[2 * t], c1 = cnt[2 * t + 1];
    psum[t] = c0 + c1;
    __syncthreads();
    for (int off = 1; off < 256; off <<= 1) {
        int u = (t >= off) ? psum[t - off] : 0;
        __syncthreads();
        psum[t] += u;
        __syncthreads();
    }
    int excl = psum[t] - c0 - c1;
    curs[2 * t] = excl;
    curs[2 * t + 1] = excl + c0;
    int n0 = node0 + 2 * t;
    if (n0 < N_NODES)     rowptr[n0]     = eb + excl;
    if (n0 + 1 < N_NODES) rowptr[n0 + 1] = eb + excl + c0;
    if (b == gridDim.x - 1 && t == 0) rowptr[N_NODES] = ee;
    __syncthreads();
    for (int e = eb + t; e < ee; e += 256) {
        int p = dstPart[e];
        int loc = ((unsigned)p) >> 20;
        int pos = eb + atomicAdd(&curs[loc], 1);
        cv[pos] = p & 0xFFFFF;
    }
}

// ---- P3b: per-bucket src-degree histogram -> dinv ----
__global__ __launch_bounds__(256) void degs_kernel(const int* __restrict__ baseS,
        const u16* __restrict__ srcPart, float* __restrict__ dinv) {
    __shared__ int cnt[BSZ];
    int b = blockIdx.x, t = threadIdx.x;
    int eb = baseS[b], ee = baseS[b + 1];
    for (int i = t; i < BSZ; i += 256) cnt[i] = 0;
    __syncthreads();
    for (int e = eb + t; e < ee; e += 256)
        atomicAdd(&cnt[srcPart[e]], 1);
    __syncthreads();
    for (int i = t; i < BSZ; i += 256) {
        int node = b * BSZ + i;
        if (node < N_NODES) {
            int d = cnt[i];
            dinv[node] = (d > 0) ? rsqrtf((float)d) : 0.0f;
        }
    }
}

// ---- x -> gx = dinv * x (bf16) ----
__global__ __launch_bounds__(256) void cvt_kernel(const float* __restrict__ x,
        const float* __restrict__ dinv, u16* __restrict__ gx, int nvec) {
    int i = blockIdx.x * blockDim.x + threadIdx.x;
    if (i >= nvec) return;
    float4 v = ((const float4*)x)[i];
    float dv = dinv[i >> 4];
    uint2 b;
    b.x = (uint)f2b(v.x * dv) | ((uint)f2b(v.y * dv) << 16);
    b.y = (uint)f2b(v.z * dv) | ((uint)f2b(v.w * dv) << 16);
    ((uint2*)gx)[i] = b;
}

// ---- propagate: out[i] = -dinv[i] * sum_e g[src_e] (g pre-scaled by dinv) ----
__global__ __launch_bounds__(256) void gather_kernel(const int* __restrict__ rowptr,
        const int* __restrict__ cv, const u16* __restrict__ g,
        const float* __restrict__ dinv, u16* __restrict__ outp,
        u16* __restrict__ outscaled, int n) {
    int lane = threadIdx.x & 63;
    int node = __builtin_amdgcn_readfirstlane(blockIdx.x * 4 + (threadIdx.x >> 6));
    if (node >= n) return;
    int p = rowptr[node];
    const int pe = rowptr[node + 1];
    float a0 = 0.0f, a1 = 0.0f, a2 = 0.0f, a3 = 0.0f;
    for (; p + 3 < pe; p += 4) {
        int s0 = cv[p + 0];
        int s1 = cv[p + 1];
        int s2 = cv[p + 2];
        int s3 = cv[p + 3];
        a0 += b2f(g[(size_t)s0 * D + lane]);
        a1 += b2f(g[(size_t)s1 * D + lane]);
        a2 += b2f(g[(size_t)s2 * D + lane]);
        a3 += b2f(g[(size_t)s3 * D + lane]);
    }
    for (; p < pe; ++p)
        a0 += b2f(g[(size_t)cv[p] * D + lane]);
    float dv = dinv[node];
    float v = -dv * ((a0 + a1) + (a2 + a3));
    size_t ob = (size_t)node * D + lane;
    outp[ob] = f2b(v);
    if (outscaled) outscaled[ob] = f2b(dv * v);
}

// ---- MFMA epilogue: O[NPAD x 64] = [Tx0 | Tx1 | 2*Tx2-Tx0] @ Wcat + b (+skip), relu ----
// Block: 4 waves = 2M x 2N; wave tile M=32 (2 mi), N=32 (2 ni), K=192 (6 kt of 32).
// mfma_f32_16x16x32_bf16. A row = lane&15, k = (lane>>4)*8+j. B col = lane&15, same k.
// C: col = lane&15, row = (lane>>4)*4 + reg (m89-verified).
__global__ __launch_bounds__(256) void cheb_mfma_kernel(
        const float* __restrict__ x,      // f32 input (layer 0)
        const u16* __restrict__ inp,      // bf16 h_prev (layers > 0)
        const u16* __restrict__ t1, const u16* __restrict__ t2,
        const float* __restrict__ W, const float* __restrict__ bias,
        const float* __restrict__ dinv,
        u16* __restrict__ outb, u16* __restrict__ goutb, float* __restrict__ outf,
        int addSkip, int writeScaled, int outF32, int inpF32) {
    const int tid = threadIdx.x;
    const int lane = tid & 63;
    const int w = tid >> 6;
    const int wm = w & 1, wn = w >> 1;
    const int l15 = lane & 15;
    const int l4 = lane >> 4;        // 0..3
    const int koff = l4 * 8;

    const int mbase = blockIdx.x * 64 + wm * 32;
    const int nbase = wn * 32;

    // ---- preload B fragments (weights -> bf16) ----
    short8 Bf[6][2];
#pragma unroll
    for (int kt = 0; kt < 6; ++kt)
#pragma unroll
        for (int ni = 0; ni < 2; ++ni) {
            const float* wp = W + (size_t)(kt * 32 + koff) * 64 + nbase + ni * 16 + l15;
#pragma unroll
            for (int j = 0; j < 8; ++j)
                Bf[kt][ni][j] = (short)f2b(wp[(size_t)j * 64]);
        }

    // ---- hoist inp-dependent A data before barrier (inp may alias outb) ----
    short8 Fi[2][2];   // [mi][half]: inp rows, k = half*32 + koff + j
    if (!inpF32) {
#pragma unroll
        for (int mi = 0; mi < 2; ++mi)
#pragma unroll
            for (int half = 0; half < 2; ++half) {
                int row = mbase + mi * 16 + l15;
                Fi[mi][half] = *(const short8*)(inp + (size_t)row * 64 + half * 32 + koff);
            }
        __syncthreads();   // drains loads; no wave stores h before all have read it
    }

    f32x4 acc[2][2];
#pragma unroll
    for (int mi = 0; mi < 2; ++mi)
#pragma unroll
        for (int ni = 0; ni < 2; ++ni)
#pragma unroll
            for (int r = 0; r < 4; ++r) acc[mi][ni][r] = 0.0f;

#pragma unroll
    for (int kt = 0; kt < 6; ++kt) {
        short8 Af[2];
#pragma unroll
        for (int mi = 0; mi < 2; ++mi) {
            int row = mbase + mi * 16 + l15;
            int rowc = min(row, N_NODES - 1);   // clamp for exact-size f32 x
            int kg = kt * 32 + koff;
            short8 a;
            if (kt < 2) {
                if (inpF32) {
                    const float* p = x + (size_t)rowc * 64 + kg;
#pragma unroll
                    for (int j = 0; j < 8; ++j) a[j] = (short)f2b(p[j]);
                } else {
                    a = Fi[mi][kt];
                }
            } else if (kt < 4) {
                a = *(const short8*)(t1 + (size_t)row * 64 + (kg - 64));
            } else {
                short8 a2 = *(const short8*)(t2 + (size_t)row * 64 + (kg - 128));
                if (inpF32) {
                    const float* p = x + (size_t)rowc * 64 + (kg - 128);
#pragma unroll
                    for (int j = 0; j < 8; ++j)
                        a[j] = (short)f2b(fmaf(2.0f, b2f((u16)a2[j]), -p[j]));
                } else {
                    short8 ai = Fi[mi][kt - 4];
#pragma unroll
                    for (int j = 0; j < 8; ++j)
                        a[j] = (short)f2b(fmaf(2.0f, b2f((u16)a2[j]), -b2f((u16)ai[j])));
                }
            }
            Af[mi] = a;
        }
#pragma unroll
        for (int mi = 0; mi < 2; ++mi)
#pragma unroll
            for (int ni = 0; ni < 2; ++ni)
                acc[mi][ni] = __builtin_amdgcn_mfma_f32_16x16x32_bf16(
                    Af[mi], Bf[kt][ni], acc[mi][ni], 0, 0, 0);
    }

    // ---- epilogue: bias + skip + relu + stores ----
    float bj0 = bias[nbase + l15];
    float bj1 = bias[nbase + 16 + l15];
#pragma unroll
    for (int mi = 0; mi < 2; ++mi)
#pragma unroll
        for (int r = 0; r < 4; ++r) {
            int node = mbase + mi * 16 + l4 * 4 + r;
            if (node >= N_NODES) continue;
            float dv = writeScaled ? dinv[node] : 0.0f;
#pragma unroll
            for (int ni = 0; ni < 2; ++ni) {
                int col = nbase + ni * 16 + l15;
                size_t o = (size_t)node * 64 + col;
                float v = acc[mi][ni][r] + (ni ? bj1 : bj0);
                if (addSkip) v += b2f(inp[o]);
                v = fmaxf(v, 0.0f);
                if (outF32) {
                    outf[o] = v;
                } else {
                    outb[o] = f2b(v);
                    if (writeScaled) goutb[o] = f2b(v * dv);
                }
            }
        }
}

extern "C" void kernel_launch(void* const* d_in, const int* in_sizes, int n_in,
                              void* d_out, int out_size, void* d_ws, size_t ws_size,
                              hipStream_t stream) {
    const float* x = (const float*)d_in[0];
    const int* ei = (const int*)d_in[1];
    const float* W = (const float*)d_in[2];   // [3,3,64,64]
    const float* b = (const float*)d_in[3];   // [3,64]
    float* out = (float*)d_out;

    const int* src = ei;
    const int* dst = ei + N_EDGES;

    const size_t NDP = (size_t)NPAD * D;

    char* w = (char*)d_ws;
    int*   cnt2   = (int*)w;        w += (size_t)(2 * NB) * 4;
    int*   base2  = (int*)w;        w += (size_t)(2 * (NB + 1)) * 4;
    int*   curs2  = (int*)w;        w += (size_t)(2 * NB) * 4;
    int*   rowptr = (int*)w;        w += (size_t)(N_NODES + 4) * 4;
    float* dinv   = (float*)w;      w += (size_t)N_NODES * 4;
    int*   cv     = (int*)w;        w += (size_t)N_EDGES * 4;
    u16*   gx     = (u16*)w;        w += NDP * 2;
    u16*   h      = (u16*)w;        w += NDP * 2;
    u16*   gh     = (u16*)w;        w += NDP * 2;
    u16*   t1     = (u16*)w;        w += NDP * 2;
    u16*   gt1    = (u16*)w;        w += NDP * 2;
    u16*   t2     = (u16*)w;        w += NDP * 2;
    // partition buffers alias gt1/t2 (first real use is after CSR build)
    int*   dstPart = (int*)gt1;     // 4.8 MB <= 12.8 MB
    u16*   srcPart = (u16*)t2;      // 2.4 MB <= 12.8 MB

    int* baseD = base2;
    int* baseS = base2 + (NB + 1);
    int* cursD = curs2;
    int* cursS = curs2 + NB;

    // ---- CSR build (bucketed radix partition, LDS atomics) ----
    hipMemsetAsync(cnt2, 0, (size_t)(2 * NB) * 4, stream);
    hist_kernel<<<304, 256, 0, stream>>>(src, dst, cnt2, N_EDGES);
    scanb_kernel<<<1, 256, 0, stream>>>(cnt2, base2, curs2);
    part_kernel<<<NCHUNK, 256, 0, stream>>>(src, dst, cursD, cursS, dstPart, srcPart, N_EDGES);
    csr_kernel<<<NB, 256, 0, stream>>>(baseD, dstPart, rowptr, cv);
    degs_kernel<<<NB, 256, 0, stream>>>(baseS, srcPart, dinv);
    cvt_kernel<<<(int)(((size_t)N_NODES * D / 4 + 255) / 256), 256, 0, stream>>>(
        x, dinv, gx, (int)((size_t)N_NODES * D / 4));

    const int gatherBlocks = (N_NODES + 3) / 4;
    const int chebBlocks = NPAD / 64;   // 1568

    for (int l = 0; l < NUM_LAYERS; ++l) {
        const u16* gin = (l == 0) ? gx : gh;
        gather_kernel<<<gatherBlocks, 256, 0, stream>>>(rowptr, cv, gin, dinv, t1, gt1, N_NODES);
        gather_kernel<<<gatherBlocks, 256, 0, stream>>>(rowptr, cv, gt1, dinv, t2, (u16*)0, N_NODES);

        int last = (l == NUM_LAYERS - 1);
        cheb_mfma_kernel<<<chebBlocks, 256, 0, stream>>>(
            x, h, t1, t2, W + (size_t)l * 3 * D * D, b + (size_t)l * D, dinv,
            h, gh, out,
            /*addSkip=*/l > 0, /*writeScaled=*/!last, /*outF32=*/last, /*inpF32=*/l == 0);
    }
}

// Round 7
// 383.889 us; speedup vs baseline: 8.9625x; 1.2079x over previous
//
#include <hip/hip_runtime.h>

#define N_NODES 100000
#define N_EDGES 1200000
#define D 64
#define NUM_LAYERS 3

#define NB 196          // coarse buckets
#define BSZ 512         // nodes per bucket (NB*BSZ = 100352 >= N_NODES)
#define NPAD (NB * BSZ) // padded node count (100352, multiple of 64)
#define CHUNK 4096      // edges per partition block
#define NCHUNK ((N_EDGES + CHUNK - 1) / CHUNK)   // 293
#define ZROW N_NODES    // dummy src row (zeroed) for list padding
#define BSLACK 3592     // per-bucket pad slack: 512*7 + 8 (alignment-safe)

typedef unsigned int uint;
typedef unsigned short u16;

using short8 = __attribute__((ext_vector_type(8))) short;
using f32x4  = __attribute__((ext_vector_type(4))) float;

static __device__ __forceinline__ float b2f(u16 u) {
    return __uint_as_float(((uint)u) << 16);
}
static __device__ __forceinline__ u16 f2b(float f) {
    uint u = __float_as_uint(f);
    return (u16)((u + 0x7FFFu + ((u >> 16) & 1u)) >> 16);
}

// ---- P1: coarse bucket histograms (dst and src) via LDS ----
__global__ __launch_bounds__(256) void hist_kernel(const int* __restrict__ src,
        const int* __restrict__ dst, int* __restrict__ cnt2, int E) {
    __shared__ int hD[NB], hS[NB];
    for (int i = threadIdx.x; i < NB; i += 256) { hD[i] = 0; hS[i] = 0; }
    __syncthreads();
    int i = blockIdx.x * 256 + threadIdx.x;
    int stride = gridDim.x * 256;
    for (; i < E; i += stride) {
        atomicAdd(&hD[((unsigned)dst[i]) >> 9], 1);
        atomicAdd(&hS[((unsigned)src[i]) >> 9], 1);
    }
    __syncthreads();
    for (int i2 = threadIdx.x; i2 < NB; i2 += 256) {
        if (hD[i2]) atomicAdd(&cnt2[i2], hD[i2]);
        if (hS[i2]) atomicAdd(&cnt2[NB + i2], hS[i2]);
    }
}

// ---- P2a: scan bucket counts -> bases + cursors ----
__global__ __launch_bounds__(256) void scanb_kernel(const int* __restrict__ cnt2,
        int* __restrict__ base2, int* __restrict__ curs2) {
    __shared__ int buf[256];
    int t = threadIdx.x;
    for (int arr = 0; arr < 2; ++arr) {
        int v = (t < NB) ? cnt2[arr * NB + t] : 0;
        buf[t] = v;
        __syncthreads();
        for (int off = 1; off < 256; off <<= 1) {
            int u = (t >= off) ? buf[t - off] : 0;
            __syncthreads();
            buf[t] += u;
            __syncthreads();
        }
        int excl = buf[t] - v;
        if (t < NB) {
            base2[arr * (NB + 1) + t] = excl;
            curs2[arr * NB + t] = excl;
        }
        if (t == NB - 1) base2[arr * (NB + 1) + NB] = buf[t];
        __syncthreads();
    }
}

// ---- P2b: partition edges into coarse buckets (LDS-staged chunks) ----
__global__ __launch_bounds__(256) void part_kernel(const int* __restrict__ src,
        const int* __restrict__ dst, int* __restrict__ cursD, int* __restrict__ cursS,
        int* __restrict__ dstPart, u16* __restrict__ srcPart, int E) {
    __shared__ int eS[CHUNK], eT[CHUNK];
    __shared__ int hD[NB], hS[NB], bD[NB], bS[NB];
    int e0 = blockIdx.x * CHUNK;
    int n = min(CHUNK, E - e0);
    for (int i = threadIdx.x; i < NB; i += 256) { hD[i] = 0; hS[i] = 0; }
    for (int i = threadIdx.x; i < n; i += 256) { eS[i] = src[e0 + i]; eT[i] = dst[e0 + i]; }
    __syncthreads();
    for (int i = threadIdx.x; i < n; i += 256) {
        atomicAdd(&hD[((unsigned)eT[i]) >> 9], 1);
        atomicAdd(&hS[((unsigned)eS[i]) >> 9], 1);
    }
    __syncthreads();
    for (int i = threadIdx.x; i < NB; i += 256) {
        bD[i] = hD[i] ? atomicAdd(&cursD[i], hD[i]) : 0;
        bS[i] = hS[i] ? atomicAdd(&cursS[i], hS[i]) : 0;
        hD[i] = 0; hS[i] = 0;          // reuse as local cursors
    }
    __syncthreads();
    for (int i = threadIdx.x; i < n; i += 256) {
        int s = eS[i], t = eT[i];
        int kb = ((unsigned)t) >> 9;
        int pos = bD[kb] + atomicAdd(&hD[kb], 1);
        dstPart[pos] = ((t & 511) << 20) | s;
        kb = ((unsigned)s) >> 9;
        pos = bS[kb] + atomicAdd(&hS[kb], 1);
        srcPart[pos] = (u16)(s & 511);
    }
}

// ---- P3a: per-bucket CSR, lists padded to multiples of 8 (dummy = ZROW) ----
__global__ __launch_bounds__(256) void csr_kernel(const int* __restrict__ baseD,
        const int* __restrict__ dstPart, int* __restrict__ rowptr,
        int* __restrict__ rowend, int* __restrict__ cv) {
    __shared__ int cnt[BSZ], curs[BSZ], psum[256];
    int b = blockIdx.x, t = threadIdx.x;
    int node0 = b * BSZ;
    int eb = baseD[b], ee = baseD[b + 1];
    int padbase = ((eb + 7) & ~7) + b * BSLACK;   // 8-aligned, non-overlapping
    for (int i = t; i < BSZ; i += 256) cnt[i] = 0;
    __syncthreads();
    for (int e = eb + t; e < ee; e += 256)
        atomicAdd(&cnt[((unsigned)dstPart[e]) >> 20], 1);
    __syncthreads();
    int c0 = cnt[2 * t], c1 = cnt[2 * t + 1];
    int p0 = (c0 + 7) & ~7, p1 = (c1 + 7) & ~7;
    psum[t] = p0 + p1;
    __syncthreads();
    for (int off = 1; off < 256; off <<= 1) {
        int u = (t >= off) ? psum[t - off] : 0;
        __syncthreads();
        psum[t] += u;
        __syncthreads();
    }
    int excl = psum[t] - p0 - p1;
    int start0 = padbase + excl;
    int start1 = start0 + p0;
    curs[2 * t] = start0;
    curs[2 * t + 1] = start1;
    int n0 = node0 + 2 * t;
    if (n0 < N_NODES)     { rowptr[n0]     = start0; rowend[n0]     = start0 + p0; }
    if (n0 + 1 < N_NODES) { rowptr[n0 + 1] = start1; rowend[n0 + 1] = start1 + p1; }
    __syncthreads();
    for (int e = eb + t; e < ee; e += 256) {
        int p = dstPart[e];
        int loc = ((unsigned)p) >> 20;
        int pos = atomicAdd(&curs[loc], 1);
        cv[pos] = p & 0xFFFFF;
    }
    __syncthreads();
    // fill dummy tail slots
    for (int q = c0; q < p0; ++q) cv[start0 + q] = ZROW;
    for (int q = c1; q < p1; ++q) cv[start1 + q] = ZROW;
}

// ---- P3b: per-bucket src-degree histogram -> dinv ----
__global__ __launch_bounds__(256) void degs_kernel(const int* __restrict__ baseS,
        const u16* __restrict__ srcPart, float* __restrict__ dinv) {
    __shared__ int cnt[BSZ];
    int b = blockIdx.x, t = threadIdx.x;
    int eb = baseS[b], ee = baseS[b + 1];
    for (int i = t; i < BSZ; i += 256) cnt[i] = 0;
    __syncthreads();
    for (int e = eb + t; e < ee; e += 256)
        atomicAdd(&cnt[srcPart[e]], 1);
    __syncthreads();
    for (int i = t; i < BSZ; i += 256) {
        int node = b * BSZ + i;
        if (node < N_NODES) {
            int d = cnt[i];
            dinv[node] = (d > 0) ? rsqrtf((float)d) : 0.0f;
        }
    }
}

// ---- x -> gx = dinv * x (bf16) ----
__global__ __launch_bounds__(256) void cvt_kernel(const float* __restrict__ x,
        const float* __restrict__ dinv, u16* __restrict__ gx, int nvec) {
    int i = blockIdx.x * blockDim.x + threadIdx.x;
    if (i >= nvec) return;
    float4 v = ((const float4*)x)[i];
    float dv = dinv[i >> 4];
    uint2 b;
    b.x = (uint)f2b(v.x * dv) | ((uint)f2b(v.y * dv) << 16);
    b.y = (uint)f2b(v.z * dv) | ((uint)f2b(v.w * dv) << 16);
    ((uint2*)gx)[i] = b;
}

// ---- propagate: out[i] = -dinv[i] * sum_e g[src_e] (g pre-scaled by dinv) ----
// one wave per dst node; padded lists (multiple of 8, 8-aligned starts);
// deep pipeline: 16-edge fast path / pipelined 8-wide general path.
__global__ __launch_bounds__(256) void gather_kernel(const int* __restrict__ rowptr,
        const int* __restrict__ rowend, const int* __restrict__ cv,
        const u16* __restrict__ g, const float* __restrict__ dinv,
        u16* __restrict__ outp, u16* __restrict__ outscaled, int n) {
    int lane = threadIdx.x & 63;
    int node = __builtin_amdgcn_readfirstlane((int)(blockIdx.x * 4) + (threadIdx.x >> 6));
    if (node >= n) return;
    int p = rowptr[node];
    const int pe = rowend[node];
    const int len = pe - p;
    float a0 = 0.f, a1 = 0.f, a2 = 0.f, a3 = 0.f,
          a4 = 0.f, a5 = 0.f, a6 = 0.f, a7 = 0.f;
    if (len == 16) {
        int4 c0 = *(const int4*)(cv + p);
        int4 c1 = *(const int4*)(cv + p + 4);
        int4 c2 = *(const int4*)(cv + p + 8);
        int4 c3 = *(const int4*)(cv + p + 12);
        float v0  = b2f(g[(size_t)c0.x * D + lane]);
        float v1  = b2f(g[(size_t)c0.y * D + lane]);
        float v2  = b2f(g[(size_t)c0.z * D + lane]);
        float v3  = b2f(g[(size_t)c0.w * D + lane]);
        float v4  = b2f(g[(size_t)c1.x * D + lane]);
        float v5  = b2f(g[(size_t)c1.y * D + lane]);
        float v6  = b2f(g[(size_t)c1.z * D + lane]);
        float v7  = b2f(g[(size_t)c1.w * D + lane]);
        float v8  = b2f(g[(size_t)c2.x * D + lane]);
        float v9  = b2f(g[(size_t)c2.y * D + lane]);
        float v10 = b2f(g[(size_t)c2.z * D + lane]);
        float v11 = b2f(g[(size_t)c2.w * D + lane]);
        float v12 = b2f(g[(size_t)c3.x * D + lane]);
        float v13 = b2f(g[(size_t)c3.y * D + lane]);
        float v14 = b2f(g[(size_t)c3.z * D + lane]);
        float v15 = b2f(g[(size_t)c3.w * D + lane]);
        a0 = (v0 + v8);  a1 = (v1 + v9);  a2 = (v2 + v10); a3 = (v3 + v11);
        a4 = (v4 + v12); a5 = (v5 + v13); a6 = (v6 + v14); a7 = (v7 + v15);
    } else if (len > 0) {
        int4 ca = *(const int4*)(cv + p);
        int4 cb = *(const int4*)(cv + p + 4);
        for (;;) {
            int np = p + 8;
            bool more = np < pe;
            int4 na, nb;
            if (more) {                    // prefetch next round's cv early
                na = *(const int4*)(cv + np);
                nb = *(const int4*)(cv + np + 4);
            }
            a0 += b2f(g[(size_t)ca.x * D + lane]);
            a1 += b2f(g[(size_t)ca.y * D + lane]);
            a2 += b2f(g[(size_t)ca.z * D + lane]);
            a3 += b2f(g[(size_t)ca.w * D + lane]);
            a4 += b2f(g[(size_t)cb.x * D + lane]);
            a5 += b2f(g[(size_t)cb.y * D + lane]);
            a6 += b2f(g[(size_t)cb.z * D + lane]);
            a7 += b2f(g[(size_t)cb.w * D + lane]);
            if (!more) break;
            ca = na; cb = nb; p = np;
        }
    }
    float dv = dinv[node];
    float v = -dv * (((a0 + a1) + (a2 + a3)) + ((a4 + a5) + (a6 + a7)));
    size_t ob = (size_t)node * D + lane;
    outp[ob] = f2b(v);
    if (outscaled) outscaled[ob] = f2b(dv * v);
}

// ---- MFMA epilogue: O[NPAD x 64] = [Tx0 | Tx1 | 2*Tx2-Tx0] @ Wcat + b (+skip), relu ----
__global__ __launch_bounds__(256) void cheb_mfma_kernel(
        const float* __restrict__ x,      // f32 input (layer 0)
        const u16* __restrict__ inp,      // bf16 h_prev (layers > 0)
        const u16* __restrict__ t1, const u16* __restrict__ t2,
        const float* __restrict__ W, const float* __restrict__ bias,
        const float* __restrict__ dinv,
        u16* __restrict__ outb, u16* __restrict__ goutb, float* __restrict__ outf,
        int addSkip, int writeScaled, int outF32, int inpF32) {
    const int tid = threadIdx.x;
    const int lane = tid & 63;
    const int w = tid >> 6;
    const int wm = w & 1, wn = w >> 1;
    const int l15 = lane & 15;
    const int l4 = lane >> 4;        // 0..3
    const int koff = l4 * 8;

    const int mbase = blockIdx.x * 64 + wm * 32;
    const int nbase = wn * 32;

    short8 Bf[6][2];
#pragma unroll
    for (int kt = 0; kt < 6; ++kt)
#pragma unroll
        for (int ni = 0; ni < 2; ++ni) {
            const float* wp = W + (size_t)(kt * 32 + koff) * 64 + nbase + ni * 16 + l15;
#pragma unroll
            for (int j = 0; j < 8; ++j)
                Bf[kt][ni][j] = (short)f2b(wp[(size_t)j * 64]);
        }

    short8 Fi[2][2];   // [mi][half]: inp rows, k = half*32 + koff + j
    if (!inpF32) {
#pragma unroll
        for (int mi = 0; mi < 2; ++mi)
#pragma unroll
            for (int half = 0; half < 2; ++half) {
                int row = mbase + mi * 16 + l15;
                Fi[mi][half] = *(const short8*)(inp + (size_t)row * 64 + half * 32 + koff);
            }
        __syncthreads();   // drains loads; no wave stores h before all have read it
    }

    f32x4 acc[2][2];
#pragma unroll
    for (int mi = 0; mi < 2; ++mi)
#pragma unroll
        for (int ni = 0; ni < 2; ++ni)
#pragma unroll
            for (int r = 0; r < 4; ++r) acc[mi][ni][r] = 0.0f;

#pragma unroll
    for (int kt = 0; kt < 6; ++kt) {
        short8 Af[2];
#pragma unroll
        for (int mi = 0; mi < 2; ++mi) {
            int row = mbase + mi * 16 + l15;
            int rowc = min(row, N_NODES - 1);   // clamp for exact-size f32 x
            int kg = kt * 32 + koff;
            short8 a;
            if (kt < 2) {
                if (inpF32) {
                    const float* p = x + (size_t)rowc * 64 + kg;
#pragma unroll
                    for (int j = 0; j < 8; ++j) a[j] = (short)f2b(p[j]);
                } else {
                    a = Fi[mi][kt];
                }
            } else if (kt < 4) {
                a = *(const short8*)(t1 + (size_t)row * 64 + (kg - 64));
            } else {
                short8 a2 = *(const short8*)(t2 + (size_t)row * 64 + (kg - 128));
                if (inpF32) {
                    const float* p = x + (size_t)rowc * 64 + (kg - 128);
#pragma unroll
                    for (int j = 0; j < 8; ++j)
                        a[j] = (short)f2b(fmaf(2.0f, b2f((u16)a2[j]), -p[j]));
                } else {
                    short8 ai = Fi[mi][kt - 4];
#pragma unroll
                    for (int j = 0; j < 8; ++j)
                        a[j] = (short)f2b(fmaf(2.0f, b2f((u16)a2[j]), -b2f((u16)ai[j])));
                }
            }
            Af[mi] = a;
        }
#pragma unroll
        for (int mi = 0; mi < 2; ++mi)
#pragma unroll
            for (int ni = 0; ni < 2; ++ni)
                acc[mi][ni] = __builtin_amdgcn_mfma_f32_16x16x32_bf16(
                    Af[mi], Bf[kt][ni], acc[mi][ni], 0, 0, 0);
    }

    float bj0 = bias[nbase + l15];
    float bj1 = bias[nbase + 16 + l15];
#pragma unroll
    for (int mi = 0; mi < 2; ++mi)
#pragma unroll
        for (int r = 0; r < 4; ++r) {
            int node = mbase + mi * 16 + l4 * 4 + r;
            if (node >= N_NODES) continue;
            float dv = writeScaled ? dinv[node] : 0.0f;
#pragma unroll
            for (int ni = 0; ni < 2; ++ni) {
                int col = nbase + ni * 16 + l15;
                size_t o = (size_t)node * 64 + col;
                float v = acc[mi][ni][r] + (ni ? bj1 : bj0);
                if (addSkip) v += b2f(inp[o]);
                v = fmaxf(v, 0.0f);
                if (outF32) {
                    outf[o] = v;
                } else {
                    outb[o] = f2b(v);
                    if (writeScaled) goutb[o] = f2b(v * dv);
                }
            }
        }
}

extern "C" void kernel_launch(void* const* d_in, const int* in_sizes, int n_in,
                              void* d_out, int out_size, void* d_ws, size_t ws_size,
                              hipStream_t stream) {
    const float* x = (const float*)d_in[0];
    const int* ei = (const int*)d_in[1];
    const float* W = (const float*)d_in[2];   // [3,3,64,64]
    const float* b = (const float*)d_in[3];   // [3,64]
    float* out = (float*)d_out;

    const int* src = ei;
    const int* dst = ei + N_EDGES;

    const size_t NDP = (size_t)NPAD * D;
    const size_t CVSZ = (size_t)N_EDGES + 8 + (size_t)NB * BSLACK;  // padded cv entries

    char* w = (char*)d_ws;
    int*   cnt2   = (int*)w;        w += (size_t)512 * 4;
    int*   base2  = (int*)w;        w += (size_t)512 * 4;
    int*   curs2  = (int*)w;        w += (size_t)512 * 4;
    int*   rowptr = (int*)w;        w += (size_t)NPAD * 4;
    int*   rowend = (int*)w;        w += (size_t)NPAD * 4;
    float* dinv   = (float*)w;      w += (size_t)NPAD * 4;
    int*   cv     = (int*)w;        w += ((CVSZ + 63) & ~(size_t)63) * 4;
    u16*   gx     = (u16*)w;        w += NDP * 2;
    u16*   h      = (u16*)w;        w += NDP * 2;
    u16*   gh     = (u16*)w;        w += NDP * 2;
    u16*   t1     = (u16*)w;        w += NDP * 2;
    u16*   gt1    = (u16*)w;        w += NDP * 2;
    u16*   t2     = (u16*)w;        w += NDP * 2;
    // partition buffers alias gt1/t2 (first real use is after CSR build; ZROW
    // row offset 12.8MB is beyond dstPart's 4.8MB / srcPart's 2.4MB)
    int*   dstPart = (int*)gt1;
    u16*   srcPart = (u16*)t2;

    int* baseD = base2;
    int* baseS = base2 + (NB + 1);
    int* cursD = curs2;
    int* cursS = curs2 + NB;

    // ---- CSR build (bucketed radix partition, LDS atomics, padded lists) ----
    hipMemsetAsync(cnt2, 0, (size_t)(2 * NB) * 4, stream);
    hist_kernel<<<304, 256, 0, stream>>>(src, dst, cnt2, N_EDGES);
    scanb_kernel<<<1, 256, 0, stream>>>(cnt2, base2, curs2);
    part_kernel<<<NCHUNK, 256, 0, stream>>>(src, dst, cursD, cursS, dstPart, srcPart, N_EDGES);
    csr_kernel<<<NB, 256, 0, stream>>>(baseD, dstPart, rowptr, rowend, cv);
    degs_kernel<<<NB, 256, 0, stream>>>(baseS, srcPart, dinv);
    // zero the dummy row in every gather source buffer
    hipMemsetAsync(gx  + (size_t)ZROW * D, 0, D * 2, stream);
    hipMemsetAsync(gh  + (size_t)ZROW * D, 0, D * 2, stream);
    hipMemsetAsync(gt1 + (size_t)ZROW * D, 0, D * 2, stream);
    cvt_kernel<<<(int)(((size_t)N_NODES * D / 4 + 255) / 256), 256, 0, stream>>>(
        x, dinv, gx, (int)((size_t)N_NODES * D / 4));

    const int gatherBlocks = (N_NODES + 3) / 4;
    const int chebBlocks = NPAD / 64;   // 1568

    for (int l = 0; l < NUM_LAYERS; ++l) {
        const u16* gin = (l == 0) ? gx : gh;
        gather_kernel<<<gatherBlocks, 256, 0, stream>>>(rowptr, rowend, cv, gin, dinv, t1, gt1, N_NODES);
        gather_kernel<<<gatherBlocks, 256, 0, stream>>>(rowptr, rowend, cv, gt1, dinv, t2, (u16*)0, N_NODES);

        int last = (l == NUM_LAYERS - 1);
        cheb_mfma_kernel<<<chebBlocks, 256, 0, stream>>>(
            x, h, t1, t2, W + (size_t)l * 3 * D * D, b + (size_t)l * D, dinv,
            h, gh, out,
            /*addSkip=*/l > 0, /*writeScaled=*/!last, /*outF32=*/last, /*inpF32=*/l == 0);
    }
}